// Round 1
// baseline (1281.069 us; speedup 1.0000x reference)
//
#include <hip/hip_runtime.h>
#include <hip/hip_bf16.h>
#include <math.h>

#define B_ 8192
#define F_ 26
#define D_ 32
#define V_ 100000
#define NP_ 351   // 26*27/2 pairs i<=j
#define H1_ 128
#define H2_ 128
#define U1_ 400
#define U2_ 400

// ---- ws layout (bytes) ----
static const size_t OFF_V    = 0;                        // v: B x 832 f32      = 27262976
static const size_t OFF_LIN  = 27262976;                 // linear: B f32       = 32768
static const size_t OFF_CIN1 = OFF_LIN  + 32768;         // cin1: B x 128 f32   = 4194304
static const size_t OFF_CIN2 = OFF_CIN1 + 4194304;       // cin2: B x 128 f32   = 4194304
static const size_t OFF_G    = OFF_CIN2 + 4194304;       // G: B x 3328 bf16    = 54525952
static const size_t OFF_H1   = OFF_G    + 54525952;      // h1: B x 400 f32     = 13107200
static const size_t OFF_H2   = OFF_H1   + 13107200;      // h2: B x 400 f32     = 13107200
static const size_t OFF_W0S  = OFF_H2   + 13107200;      // W0sym: 351 x 128 f32 = 179712
// total ~111.2 MB

static __device__ __forceinline__ float bf2f(unsigned short u) {
    return __uint_as_float(((unsigned int)u) << 16);
}

// ---- K0: symmetrize W_cin0 into W0s[p][h], p over pairs i<=j ----
__global__ __launch_bounds__(256) void k0_w0sym(const float* __restrict__ W0,
                                                float* __restrict__ W0s) {
    int o = blockIdx.x * 256 + threadIdx.x;
    if (o >= NP_ * H1_) return;
    int p = o >> 7, h = o & 127;
    // decode p -> (i,j), i<=j
    int i = 0, base = 0;
    while (base + (F_ - i) <= p) { base += F_ - i; ++i; }
    int j = i + (p - base);
    float w = W0[(i * F_ + j) * H1_ + h];
    if (i != j) w += W0[(j * F_ + i) * H1_ + h];
    W0s[o] = w;
}

// ---- K1: per-batch-element: gather, linear, x1, cin1, G ----
__global__ __launch_bounds__(256) void k1_embed_cin(
    const int*   __restrict__ sparse,
    const float* __restrict__ E,
    const float* __restrict__ W0s,
    const float* __restrict__ wlin,
    const float* __restrict__ blin,
    float* __restrict__ v,
    float* __restrict__ lin,
    float* __restrict__ cin1,
    __hip_bfloat16* __restrict__ G)
{
    __shared__ float emb[F_][D_];        // 3328 B
    __shared__ float P[NP_][D_];         // 44928 B
    __shared__ float x1s[H1_][D_ + 1];   // 16896 B (pad 33 -> conflict-free)
    __shared__ float cin1p[H1_][2];
    __shared__ float linbuf[F_];
    __shared__ int   idxs[F_];
    __shared__ unsigned char pI[NP_], pJ[NP_];

    const int b = blockIdx.x;
    const int t = threadIdx.x;

    if (t < F_) {
        int id = sparse[b * F_ + t];
        idxs[t] = id;
        linbuf[t] = (float)id * wlin[t];
        int i = t;
        int base = 26 * i - (i * (i - 1)) / 2;
        for (int j = i; j < F_; ++j) {
            pI[base + j - i] = (unsigned char)i;
            pJ[base + j - i] = (unsigned char)j;
        }
    }
    __syncthreads();

    // gather 26 rows of 32 floats (8 float4 each) + write v
    if (t < F_ * 8) {
        int f = t >> 3, q = t & 7;
        const float4 r = *(const float4*)(E + ((size_t)f * V_ + idxs[f]) * D_ + q * 4);
        *(float4*)(&emb[f][q * 4]) = r;
        *(float4*)(v + (size_t)b * 832 + f * 32 + q * 4) = r;
    }
    if (t == 0) {
        float s = blin[0];
        for (int f = 0; f < F_; ++f) s += linbuf[f];
        lin[b] = s;
    }
    __syncthreads();

    // pair products P[p][d] = emb[i][d]*emb[j][d]
    for (int o = t; o < NP_ * D_; o += 256) {
        int p = o >> 5, d = o & 31;
        P[p][d] = emb[pI[p]][d] * emb[pJ[p]][d];
    }
    __syncthreads();

    // x1[h][d] = sum_p W0s[p][h] * P[p][d]   (thread owns h, 16 of 32 d)
    const int h = t & 127, half = t >> 7, d0 = half * 16;
    float acc[16];
#pragma unroll
    for (int q = 0; q < 16; ++q) acc[q] = 0.f;
    const float* W0sh = W0s + h;
#pragma unroll 3
    for (int p = 0; p < NP_; ++p) {
        float w = W0sh[p * H1_];
        float pv[16];
        *(float4*)&pv[0]  = *(const float4*)&P[p][d0];
        *(float4*)&pv[4]  = *(const float4*)&P[p][d0 + 4];
        *(float4*)&pv[8]  = *(const float4*)&P[p][d0 + 8];
        *(float4*)&pv[12] = *(const float4*)&P[p][d0 + 12];
#pragma unroll
        for (int q = 0; q < 16; ++q) acc[q] = fmaf(w, pv[q], acc[q]);
    }
    float csum = 0.f;
#pragma unroll
    for (int q = 0; q < 16; ++q) { x1s[h][d0 + q] = acc[q]; csum += acc[q]; }
    cin1p[h][half] = csum;
    __syncthreads();

    if (t < H1_) cin1[(size_t)b * H1_ + t] = cin1p[t][0] + cin1p[t][1];

    // G[i][j] = sum_d emb[i][d] * x1[j][d]  -> bf16, flat (i*128+j)
    for (int k = 0; k < 13; ++k) {
        int o = t + k * 256;
        int i = o >> 7, j = o & 127;
        float g = 0.f;
#pragma unroll 8
        for (int d = 0; d < D_; ++d) g = fmaf(emb[i][d], x1s[j][d], g);
        G[(size_t)b * 3328 + o] = __float2bfloat16(g);
    }
}

// ---- K2: generic fp32 SIMT GEMM, 64x64 tile, BK=16, 256 threads, 4x4 micro ----
template<bool ABF16, bool RELU, bool BIAS>
__global__ __launch_bounds__(256) void gemm_k(
    const void*  __restrict__ Av,
    const float* __restrict__ Bw,
    const float* __restrict__ bias,
    float* __restrict__ C,
    int M, int N, int K)
{
    __shared__ float As[16][68];   // [kk][m], padded row 68
    __shared__ float Bs[16][68];   // [kk][n]
    const int t  = threadIdx.x;
    const int m0 = blockIdx.y * 64, n0 = blockIdx.x * 64;
    const int ty = t >> 4, tx = t & 15;
    const int ar = t >> 2, ac = t & 3;
    const int br = t >> 4, bc = t & 15;
    float c[4][4] = {{0.f}};

    for (int k0 = 0; k0 < K; k0 += 16) {
        if (ABF16) {
            const unsigned short* A = (const unsigned short*)Av;
            ushort4 u = *(const ushort4*)(A + (size_t)(m0 + ar) * K + k0 + ac * 4);
            As[ac * 4 + 0][ar] = bf2f(u.x);
            As[ac * 4 + 1][ar] = bf2f(u.y);
            As[ac * 4 + 2][ar] = bf2f(u.z);
            As[ac * 4 + 3][ar] = bf2f(u.w);
        } else {
            const float* A = (const float*)Av;
            float4 a4 = *(const float4*)(A + (size_t)(m0 + ar) * K + k0 + ac * 4);
            As[ac * 4 + 0][ar] = a4.x;
            As[ac * 4 + 1][ar] = a4.y;
            As[ac * 4 + 2][ar] = a4.z;
            As[ac * 4 + 3][ar] = a4.w;
        }
        int col = n0 + bc * 4;
        float4 b4 = make_float4(0.f, 0.f, 0.f, 0.f);
        if (col < N) b4 = *(const float4*)(Bw + (size_t)(k0 + br) * N + col);
        *(float4*)&Bs[br][bc * 4] = b4;
        __syncthreads();
#pragma unroll
        for (int kk = 0; kk < 16; ++kk) {
            float4 a4 = *(const float4*)&As[kk][ty * 4];
            float4 b4v = *(const float4*)&Bs[kk][tx * 4];
            c[0][0] = fmaf(a4.x, b4v.x, c[0][0]); c[0][1] = fmaf(a4.x, b4v.y, c[0][1]);
            c[0][2] = fmaf(a4.x, b4v.z, c[0][2]); c[0][3] = fmaf(a4.x, b4v.w, c[0][3]);
            c[1][0] = fmaf(a4.y, b4v.x, c[1][0]); c[1][1] = fmaf(a4.y, b4v.y, c[1][1]);
            c[1][2] = fmaf(a4.y, b4v.z, c[1][2]); c[1][3] = fmaf(a4.y, b4v.w, c[1][3]);
            c[2][0] = fmaf(a4.z, b4v.x, c[2][0]); c[2][1] = fmaf(a4.z, b4v.y, c[2][1]);
            c[2][2] = fmaf(a4.z, b4v.z, c[2][2]); c[2][3] = fmaf(a4.z, b4v.w, c[2][3]);
            c[3][0] = fmaf(a4.w, b4v.x, c[3][0]); c[3][1] = fmaf(a4.w, b4v.y, c[3][1]);
            c[3][2] = fmaf(a4.w, b4v.z, c[3][2]); c[3][3] = fmaf(a4.w, b4v.w, c[3][3]);
        }
        __syncthreads();
    }

    int col = n0 + tx * 4;
    if (col < N) {
        float4 bb = make_float4(0.f, 0.f, 0.f, 0.f);
        if (BIAS) bb = *(const float4*)(bias + col);
#pragma unroll
        for (int q = 0; q < 4; ++q) {
            float4 r;
            r.x = c[q][0] + bb.x; r.y = c[q][1] + bb.y;
            r.z = c[q][2] + bb.z; r.w = c[q][3] + bb.w;
            if (RELU) {
                r.x = fmaxf(r.x, 0.f); r.y = fmaxf(r.y, 0.f);
                r.z = fmaxf(r.z, 0.f); r.w = fmaxf(r.w, 0.f);
            }
            *(float4*)(C + (size_t)(m0 + ty * 4 + q) * N + col) = r;
        }
    }
}

// ---- K3: final concat-dot + sigmoid, one wave per batch element ----
__global__ __launch_bounds__(256) void k3_final(
    const float* __restrict__ lin,
    const float* __restrict__ cin1,
    const float* __restrict__ cin2,
    const float* __restrict__ h2,
    const float* __restrict__ dense,
    const float* __restrict__ wout,
    const float* __restrict__ bout,
    float* __restrict__ out)
{
    const int wave = threadIdx.x >> 6, lane = threadIdx.x & 63;
    const int b = blockIdx.x * 4 + wave;
    float s = 0.f;
    for (int o = lane; o < 670; o += 64) {
        float f;
        if (o == 0)        f = lin[b];
        else if (o < 129)  f = cin1[(size_t)b * 128 + (o - 1)];
        else if (o < 257)  f = cin2[(size_t)b * 128 + (o - 129)];
        else if (o < 657)  f = h2[(size_t)b * 400 + (o - 257)];
        else               f = dense[(size_t)b * 13 + (o - 657)];
        s = fmaf(f, wout[o], s);
    }
#pragma unroll
    for (int off = 32; off > 0; off >>= 1) s += __shfl_down(s, off, 64);
    if (lane == 0) out[b] = 1.f / (1.f + expf(-(s + bout[0])));
}

extern "C" void kernel_launch(void* const* d_in, const int* in_sizes, int n_in,
                              void* d_out, int out_size, void* d_ws, size_t ws_size,
                              hipStream_t stream) {
    const float* dense  = (const float*)d_in[0];
    const int*   sparse = (const int*)  d_in[1];
    const float* E      = (const float*)d_in[2];
    // d_in[3] = W_cin0 (symmetrized in K0)
    const float* W0     = (const float*)d_in[3];
    const float* Wc1    = (const float*)d_in[4];   // (26,128,128) -> GEMM B (3328 x 128)
    const float* W1     = (const float*)d_in[5];
    const float* b1     = (const float*)d_in[6];
    const float* W2     = (const float*)d_in[7];
    const float* b2     = (const float*)d_in[8];
    const float* wlin   = (const float*)d_in[9];
    const float* blin   = (const float*)d_in[10];
    const float* wout   = (const float*)d_in[11];
    const float* bout   = (const float*)d_in[12];
    float* out = (float*)d_out;

    char* ws = (char*)d_ws;
    float*          v    = (float*)(ws + OFF_V);
    float*          lin  = (float*)(ws + OFF_LIN);
    float*          cin1 = (float*)(ws + OFF_CIN1);
    float*          cin2 = (float*)(ws + OFF_CIN2);
    __hip_bfloat16* G    = (__hip_bfloat16*)(ws + OFF_G);
    float*          h1   = (float*)(ws + OFF_H1);
    float*          h2   = (float*)(ws + OFF_H2);
    float*          W0s  = (float*)(ws + OFF_W0S);

    k0_w0sym<<<(NP_ * H1_ + 255) / 256, 256, 0, stream>>>(W0, W0s);
    k1_embed_cin<<<B_, 256, 0, stream>>>(sparse, E, W0s, wlin, blin, v, lin, cin1, G);
    // cin2 = G (B x 3328, bf16) @ Wc1 (3328 x 128)
    gemm_k<true,  false, false><<<dim3(2, 128), 256, 0, stream>>>(G,  Wc1, nullptr, cin2, B_, 128, 3328);
    // h1 = relu(v @ W1 + b1): (B x 832)@(832 x 400)
    gemm_k<false, true,  true ><<<dim3(7, 128), 256, 0, stream>>>(v,  W1,  b1,      h1,   B_, 400, 832);
    // h2 = relu(h1 @ W2 + b2): (B x 400)@(400 x 400)
    gemm_k<false, true,  true ><<<dim3(7, 128), 256, 0, stream>>>(h1, W2,  b2,      h2,   B_, 400, 400);
    k3_final<<<B_ / 4, 256, 0, stream>>>(lin, cin1, cin2, h2, dense, wout, bout, out);
}

// Round 2
// 616.154 us; speedup vs baseline: 2.0791x; 2.0791x over previous
//
#include <hip/hip_runtime.h>
#include <hip/hip_bf16.h>
#include <math.h>

typedef __attribute__((ext_vector_type(8))) short bf16x8;
typedef __attribute__((ext_vector_type(4))) float f32x4;

#define B_ 8192
#define F_ 26
#define D_ 32
#define V_ 100000
#define NP_ 351
#define KP_ 352   // padded K for x1 MFMA

// ---- ws layout (bytes), all 16B-aligned ----
static const size_t OFF_VB   = 0;                        // v bf16: 8192x832   = 13631488
static const size_t OFF_LIN  = 13631488;                 // f32 8192           = 32768
static const size_t OFF_CIN1 = 13664256;                 // f32 8192x128       = 4194304
static const size_t OFF_CIN2 = 17858560;                 // f32 8192x128       = 4194304
static const size_t OFF_G    = 22052864;                 // bf16 8192x3328     = 54525952
static const size_t OFF_H1B  = 76578816;                 // bf16 8192x400      = 6553600
static const size_t OFF_H2   = 83132416;                 // f32 8192x400       = 13107200
static const size_t OFF_W0T  = 96239616;                 // bf16 128x352       = 90112
static const size_t OFF_WC1T = 96329728;                 // bf16 128x3328      = 851968
static const size_t OFF_W1T  = 97181696;                 // bf16 400x832       = 665600
static const size_t OFF_W2T  = 97847296;                 // bf16 400x400       = 320000
// total 98167296 (~93.6 MB) -- under R1's 111 MB, so ws_size suffices

static __device__ __forceinline__ unsigned short f2b(float f) {
    unsigned int u = __float_as_uint(f);
    unsigned int r = (u + 0x7FFF + ((u >> 16) & 1)) >> 16;   // RNE
    return (unsigned short)r;
}
static __device__ __forceinline__ unsigned int pk2(float a, float b) {
    return (unsigned int)f2b(a) | ((unsigned int)f2b(b) << 16);
}

// ---- K0: weight prep: symmetrize W0 -> W0t[h][p] bf16; transpose others -> [n][k] bf16
__global__ __launch_bounds__(256) void k0_prep(
    const float* __restrict__ W0, const float* __restrict__ Wc1,
    const float* __restrict__ W1, const float* __restrict__ W2,
    unsigned short* __restrict__ W0t, unsigned short* __restrict__ Wc1t,
    unsigned short* __restrict__ W1t, unsigned short* __restrict__ W2t)
{
    int g = blockIdx.x * 256 + threadIdx.x;
    if (g < 128 * KP_) {
        int h = g / KP_, p = g % KP_;
        float w = 0.f;
        if (p < NP_) {
            int i = 0, base = 0;
            while (base + (F_ - i) <= p) { base += F_ - i; ++i; }
            int j = i + (p - base);
            w = W0[(i * F_ + j) * 128 + h];
            if (i != j) w += W0[(j * F_ + i) * 128 + h];
        }
        W0t[g] = f2b(w);
        return;
    }
    g -= 128 * KP_;
    if (g < 128 * 3328) { int h = g / 3328, k = g % 3328; Wc1t[g] = f2b(Wc1[(size_t)k * 128 + h]); return; }
    g -= 128 * 3328;
    if (g < 400 * 832)  { int n = g / 832,  k = g % 832;  W1t[g]  = f2b(W1[(size_t)k * 400 + n]); return; }
    g -= 400 * 832;
    if (g < 400 * 400)  { int n = g / 400,  k = g % 400;  W2t[g]  = f2b(W2[(size_t)k * 400 + n]); }
}

// ---- K1: per-b: gather, linear, x1 (MFMA), cin1, G (MFMA) ----
__global__ __launch_bounds__(256) void k1_embed_cin(
    const int*   __restrict__ sparse,
    const float* __restrict__ E,
    const unsigned short* __restrict__ W0t,
    const float* __restrict__ wlin,
    const float* __restrict__ blin,
    unsigned short* __restrict__ vb,
    float* __restrict__ lin,
    float* __restrict__ cin1,
    unsigned short* __restrict__ G)
{
    __shared__ float embf[F_][36];                         // f32 gather (stride 36: 16B-aligned rows)
    __shared__ __align__(16) unsigned short embB[32][40];  // bf16 A for G-MFMA (rows 26..31 zeroed)
    __shared__ __align__(16) unsigned short P[32][360];    // bf16 [d][p], row 720B
    __shared__ __align__(16) unsigned short x1s[128][40];  // bf16 [h][d]
    __shared__ float cin1t[2][128];
    __shared__ float linb[F_];
    __shared__ int   idxs[F_];
    __shared__ unsigned char pI[KP_], pJ[KP_];

    const int b = blockIdx.x, t = threadIdx.x;

    if (t < F_) {
        int id = sparse[b * F_ + t];
        idxs[t] = id;
        linb[t] = (float)id * wlin[t];
        int i = t, base = F_ * i - (i * (i - 1)) / 2;
        for (int j = i; j < F_; ++j) { pI[base + j - i] = (unsigned char)i; pJ[base + j - i] = (unsigned char)j; }
    }
    __syncthreads();

    if (t < 208) {  // 26 rows x 8 float4
        int f = t >> 3, q = t & 7;
        float4 r = *(const float4*)(E + ((size_t)f * V_ + idxs[f]) * D_ + q * 4);
        *(float4*)&embf[f][q * 4] = r;
        ushort4 u;
        u.x = f2b(r.x); u.y = f2b(r.y); u.z = f2b(r.z); u.w = f2b(r.w);
        *(ushort4*)&embB[f][q * 4] = u;
        *(ushort4*)(vb + (size_t)b * 832 + f * 32 + q * 4) = u;
    }
    if (t >= 208 && t < 208 + 96) {  // zero embB rows 26..31 (d 0..31)
        int o = t - 208;
        *(unsigned int*)&embB[26 + (o >> 4)][(o & 15) * 2] = 0u;
    }
    __syncthreads();

    // ---- P[d][p] = emb[i][d]*emb[j][d] (bf16), pad p=351 with 0
    {
        const int d = t & 31, pb = t >> 5;
        const int p0 = pb * 44;
        for (int k = 0; k < 22; ++k) {
            int p = p0 + 2 * k;
            float a  = embf[pI[p]][d] * embf[pJ[p]][d];
            float c2 = (p + 1 < NP_) ? embf[pI[p + 1]][d] * embf[pJ[p + 1]][d] : 0.f;
            *(unsigned int*)&P[d][p] = pk2(a, c2);
        }
        if (t == 0) { float s = blin[0]; for (int f = 0; f < F_; ++f) s += linb[f]; lin[b] = s; }
    }
    __syncthreads();

    // ---- x1 via MFMA: C[d][h] = sum_p P[d][p] * W0s[p][h], M=32, N=128, K=352
    const int wave = t >> 6, lane = t & 63;
    const int lr = lane & 15, lg = lane >> 4;
    const int mt = wave & 1, ntb = (wave >> 1) * 4;
    f32x4 acc[4] = {};
    {
        const unsigned short* Arow = &P[mt * 16 + lr][lg * 8];
        for (int kt = 0; kt < 11; ++kt) {
            bf16x8 af = *(const bf16x8*)(Arow + kt * 32);
#pragma unroll
            for (int n = 0; n < 4; ++n) {
                const unsigned short* bp = W0t + (size_t)((ntb + n) * 16 + lr) * KP_ + kt * 32 + lg * 8;
                bf16x8 bfg = *(const bf16x8*)bp;
                acc[n] = __builtin_amdgcn_mfma_f32_16x16x32_bf16(af, bfg, acc[n], 0, 0, 0);
            }
        }
    }
    // cin1 partial (sum over d) + x1 -> LDS [h][d] bf16
#pragma unroll
    for (int n = 0; n < 4; ++n) {
        float s = acc[n][0] + acc[n][1] + acc[n][2] + acc[n][3];
        s += __shfl_xor(s, 16, 64);
        s += __shfl_xor(s, 32, 64);
        int h = (ntb + n) * 16 + lr;
        if (lg == 0) cin1t[mt][h] = s;
        int d0 = mt * 16 + lg * 4;
        *(unsigned int*)&x1s[h][d0]     = pk2(acc[n][0], acc[n][1]);
        *(unsigned int*)&x1s[h][d0 + 2] = pk2(acc[n][2], acc[n][3]);
    }
    __syncthreads();

    if (t < 128) cin1[(size_t)b * 128 + t] = cin1t[0][t] + cin1t[1][t];

    // ---- G via MFMA: G[i][j] = sum_d emb[i][d]*x1[j][d], M=32, N=128, K=32
    {
        bf16x8 ea = *(const bf16x8*)&embB[mt * 16 + lr][lg * 8];
#pragma unroll
        for (int n = 0; n < 4; ++n) {
            bf16x8 xb = *(const bf16x8*)&x1s[(ntb + n) * 16 + lr][lg * 8];
            f32x4 g = {};
            g = __builtin_amdgcn_mfma_f32_16x16x32_bf16(ea, xb, g, 0, 0, 0);
            int j = (ntb + n) * 16 + lr;
            int i0 = mt * 16 + lg * 4;
#pragma unroll
            for (int r = 0; r < 4; ++r) {
                int i = i0 + r;
                if (i < F_) G[(size_t)b * 3328 + i * 128 + j] = f2b(g[r]);
            }
        }
    }
}

// ---- K2: bf16 MFMA GEMM, 64x64 tile, BK=32, 4 waves x (2x2) 16-tiles ----
// A: MxK bf16 row-major; Bt: NxK bf16 row-major (pre-transposed); C: MxN f32 or bf16
template<bool RELU, bool BIAS, bool OUTB>
__global__ __launch_bounds__(256) void gemm_mfma(
    const unsigned short* __restrict__ A,
    const unsigned short* __restrict__ Bt,
    const float* __restrict__ bias,
    void* __restrict__ C,
    int M, int N, int K)
{
    __shared__ __align__(16) unsigned short As[64][40];
    __shared__ __align__(16) unsigned short Bs[64][40];
    const int t = threadIdx.x;
    const int m0 = blockIdx.y * 64, n0 = blockIdx.x * 64;
    const int wave = t >> 6, lane = t & 63;
    const int lr = lane & 15, lg = lane >> 4;
    const int mt0 = (wave & 1) * 2, nt0 = (wave >> 1) * 2;
    const int srow = t >> 2, soff = (t & 3) * 8;

    f32x4 acc[2][2] = {};
    const int nkt = (K + 31) / 32;
    for (int kt = 0; kt < nkt; ++kt) {
        int k = kt * 32 + soff;
        uint4 av = make_uint4(0u, 0u, 0u, 0u);
        if (k < K) av = *(const uint4*)(A + (size_t)(m0 + srow) * K + k);
        *(uint4*)&As[srow][soff] = av;
        uint4 bv = make_uint4(0u, 0u, 0u, 0u);
        int n = n0 + srow;
        if (n < N && k < K) bv = *(const uint4*)(Bt + (size_t)n * K + k);
        *(uint4*)&Bs[srow][soff] = bv;
        __syncthreads();
        bf16x8 af[2], bfg[2];
#pragma unroll
        for (int i = 0; i < 2; ++i) af[i]  = *(const bf16x8*)&As[(mt0 + i) * 16 + lr][lg * 8];
#pragma unroll
        for (int j = 0; j < 2; ++j) bfg[j] = *(const bf16x8*)&Bs[(nt0 + j) * 16 + lr][lg * 8];
#pragma unroll
        for (int i = 0; i < 2; ++i)
#pragma unroll
            for (int j = 0; j < 2; ++j)
                acc[i][j] = __builtin_amdgcn_mfma_f32_16x16x32_bf16(af[i], bfg[j], acc[i][j], 0, 0, 0);
        __syncthreads();
    }
#pragma unroll
    for (int i = 0; i < 2; ++i) {
        int mrow = m0 + (mt0 + i) * 16 + lg * 4;
#pragma unroll
        for (int j = 0; j < 2; ++j) {
            int col = n0 + (nt0 + j) * 16 + lr;
            if (col >= N) continue;
            float bb = BIAS ? bias[col] : 0.f;
#pragma unroll
            for (int r = 0; r < 4; ++r) {
                float vv = acc[i][j][r] + bb;
                if (RELU) vv = fmaxf(vv, 0.f);
                if (OUTB) ((unsigned short*)C)[(size_t)(mrow + r) * N + col] = f2b(vv);
                else      ((float*)C)[(size_t)(mrow + r) * N + col] = vv;
            }
        }
    }
}

// ---- K3: final concat-dot + sigmoid, one wave per b ----
__global__ __launch_bounds__(256) void k3_final(
    const float* __restrict__ lin,
    const float* __restrict__ cin1,
    const float* __restrict__ cin2,
    const float* __restrict__ h2,
    const float* __restrict__ dense,
    const float* __restrict__ wout,
    const float* __restrict__ bout,
    float* __restrict__ out)
{
    const int wave = threadIdx.x >> 6, lane = threadIdx.x & 63;
    const int b = blockIdx.x * 4 + wave;
    float s = 0.f;
    for (int o = lane; o < 670; o += 64) {
        float f;
        if (o == 0)        f = lin[b];
        else if (o < 129)  f = cin1[(size_t)b * 128 + (o - 1)];
        else if (o < 257)  f = cin2[(size_t)b * 128 + (o - 129)];
        else if (o < 657)  f = h2[(size_t)b * 400 + (o - 257)];
        else               f = dense[(size_t)b * 13 + (o - 657)];
        s = fmaf(f, wout[o], s);
    }
#pragma unroll
    for (int off = 32; off > 0; off >>= 1) s += __shfl_down(s, off, 64);
    if (lane == 0) out[b] = 1.f / (1.f + expf(-(s + bout[0])));
}

extern "C" void kernel_launch(void* const* d_in, const int* in_sizes, int n_in,
                              void* d_out, int out_size, void* d_ws, size_t ws_size,
                              hipStream_t stream) {
    const float* dense  = (const float*)d_in[0];
    const int*   sparse = (const int*)  d_in[1];
    const float* E      = (const float*)d_in[2];
    const float* W0     = (const float*)d_in[3];
    const float* Wc1    = (const float*)d_in[4];
    const float* W1     = (const float*)d_in[5];
    const float* b1     = (const float*)d_in[6];
    const float* W2     = (const float*)d_in[7];
    const float* b2     = (const float*)d_in[8];
    const float* wlin   = (const float*)d_in[9];
    const float* blin   = (const float*)d_in[10];
    const float* wout   = (const float*)d_in[11];
    const float* bout   = (const float*)d_in[12];
    float* out = (float*)d_out;

    char* ws = (char*)d_ws;
    unsigned short* vb   = (unsigned short*)(ws + OFF_VB);
    float*          lin  = (float*)(ws + OFF_LIN);
    float*          cin1 = (float*)(ws + OFF_CIN1);
    float*          cin2 = (float*)(ws + OFF_CIN2);
    unsigned short* G    = (unsigned short*)(ws + OFF_G);
    unsigned short* h1b  = (unsigned short*)(ws + OFF_H1B);
    float*          h2   = (float*)(ws + OFF_H2);
    unsigned short* W0t  = (unsigned short*)(ws + OFF_W0T);
    unsigned short* Wc1t = (unsigned short*)(ws + OFF_WC1T);
    unsigned short* W1t  = (unsigned short*)(ws + OFF_W1T);
    unsigned short* W2t  = (unsigned short*)(ws + OFF_W2T);

    const int prep_total = 128 * KP_ + 128 * 3328 + 400 * 832 + 400 * 400;
    k0_prep<<<(prep_total + 255) / 256, 256, 0, stream>>>(W0, Wc1, W1, W2, W0t, Wc1t, W1t, W2t);
    k1_embed_cin<<<B_, 256, 0, stream>>>(sparse, E, W0t, wlin, blin, vb, lin, cin1, G);
    // cin2 = G (8192x3328) @ Wc1 (3328x128)
    gemm_mfma<false, false, false><<<dim3(2, 128), 256, 0, stream>>>(G,   Wc1t, nullptr, cin2, B_, 128, 3328);
    // h1 = relu(v @ W1 + b1), bf16 out
    gemm_mfma<true,  true,  true ><<<dim3(7, 128), 256, 0, stream>>>(vb,  W1t,  b1,      h1b,  B_, 400, 832);
    // h2 = relu(h1 @ W2 + b2), f32 out
    gemm_mfma<true,  true,  false><<<dim3(7, 128), 256, 0, stream>>>(h1b, W2t,  b2,      h2,   B_, 400, 400);
    k3_final<<<B_ / 4, 256, 0, stream>>>(lin, cin1, cin2, h2, dense, wout, bout, out);
}

// Round 3
// 582.354 us; speedup vs baseline: 2.1998x; 1.0580x over previous
//
#include <hip/hip_runtime.h>
#include <hip/hip_bf16.h>
#include <math.h>

typedef __attribute__((ext_vector_type(8))) short bf16x8;
typedef __attribute__((ext_vector_type(4))) float f32x4;

#define B_ 8192
#define F_ 26
#define D_ 32
#define V_ 100000
#define NP_ 351
#define KP_ 352   // padded K for x1 MFMA

// ---- ws layout (bytes), all 16B-aligned ----
static const size_t OFF_VB    = 0;                        // v bf16: 8192x832    = 13631488
static const size_t OFF_LIN   = 13631488;                 // f32 8192            = 32768
static const size_t OFF_CIN1  = 13664256;                 // f32 8192x128        = 4194304
static const size_t OFF_CIN2P = 17858560;                 // f32 2x8192x128      = 8388608 (split-K partials)
static const size_t OFF_G     = 26247168;                 // bf16 8192x3328      = 54525952
static const size_t OFF_H1B   = 80773120;                 // bf16 8192x400       = 6553600
static const size_t OFF_H2    = 87326720;                 // f32 8192x400        = 13107200
static const size_t OFF_W0T   = 100433920;                // bf16 128x352        = 90112
static const size_t OFF_WC1T  = 100524032;                // bf16 128x3328       = 851968
static const size_t OFF_W1T   = 101376000;                // bf16 400x832        = 665600
static const size_t OFF_W2T   = 102041600;                // bf16 400x400        = 320000
// total ~97.6 MB

static __device__ __forceinline__ unsigned short f2b(float f) {
    unsigned int u = __float_as_uint(f);
    unsigned int r = (u + 0x7FFF + ((u >> 16) & 1)) >> 16;   // RNE
    return (unsigned short)r;
}
static __device__ __forceinline__ unsigned int pk2(float a, float b) {
    return (unsigned int)f2b(a) | ((unsigned int)f2b(b) << 16);
}
static __device__ __forceinline__ float bf2f(unsigned short u) {
    return __uint_as_float(((unsigned int)u) << 16);
}

// ---- K0a: symmetrize W0 -> W0t[h][p] bf16 (p over pairs i<=j, padded to 352) ----
__global__ __launch_bounds__(256) void k0a_w0(const float* __restrict__ W0,
                                              unsigned short* __restrict__ W0t) {
    int g = blockIdx.x * 256 + threadIdx.x;
    if (g >= 128 * KP_) return;
    int h = g / KP_, p = g % KP_;
    float w = 0.f;
    if (p < NP_) {
        int i = 0, base = 0;
        while (base + (F_ - i) <= p) { base += F_ - i; ++i; }
        int j = i + (p - base);
        w = W0[(i * F_ + j) * 128 + h];
        if (i != j) w += W0[(j * F_ + i) * 128 + h];
    }
    W0t[g] = f2b(w);
}

// ---- K0b: tiled transpose f32[K][N] -> bf16[N][K], coalesced both sides ----
__global__ __launch_bounds__(256) void tkern(const float* __restrict__ src,
                                             unsigned short* __restrict__ dst,
                                             int K, int N) {
    __shared__ float tl[32][33];
    const int lx = threadIdx.x & 31, ly = threadIdx.x >> 5;
    const int n0 = blockIdx.x * 32, k0 = blockIdx.y * 32;
#pragma unroll
    for (int i = 0; i < 4; ++i) {
        int k = k0 + ly + i * 8, n = n0 + lx;
        if (k < K && n < N) tl[ly + i * 8][lx] = src[(size_t)k * N + n];
    }
    __syncthreads();
#pragma unroll
    for (int i = 0; i < 4; ++i) {
        int n = n0 + ly + i * 8, k = k0 + lx;
        if (k < K && n < N) dst[(size_t)n * K + k] = f2b(tl[lx][ly + i * 8]);
    }
}

// ---- K1: per-b: gather, linear, x1 (MFMA), cin1, G (MFMA) ----
__global__ __launch_bounds__(256) void k1_embed_cin(
    const int*   __restrict__ sparse,
    const float* __restrict__ E,
    const unsigned short* __restrict__ W0t,
    const float* __restrict__ wlin,
    const float* __restrict__ blin,
    unsigned short* __restrict__ vb,
    float* __restrict__ lin,
    float* __restrict__ cin1,
    unsigned short* __restrict__ G)
{
    __shared__ __align__(16) unsigned short embB[32][40];  // bf16 emb (rows 26..31 zero)
    __shared__ __align__(16) unsigned short P[32][360];    // bf16 [d][p]
    __shared__ __align__(16) unsigned short x1s[128][40];  // bf16 [h][d]
    __shared__ float cin1t[2][128];
    __shared__ float linb[F_];
    __shared__ int   idxs[F_];
    __shared__ unsigned char pI[KP_], pJ[KP_];

    const int b = blockIdx.x, t = threadIdx.x;

    if (t < F_) {
        int id = sparse[b * F_ + t];
        idxs[t] = id;
        linb[t] = (float)id * wlin[t];
        int i = t, base = F_ * i - (i * (i - 1)) / 2;
        for (int j = i; j < F_; ++j) { pI[base + j - i] = (unsigned char)i; pJ[base + j - i] = (unsigned char)j; }
    }
    __syncthreads();

    if (t < 208) {  // 26 rows x 8 float4
        int f = t >> 3, q = t & 7;
        float4 r = *(const float4*)(E + ((size_t)f * V_ + idxs[f]) * D_ + q * 4);
        ushort4 u;
        u.x = f2b(r.x); u.y = f2b(r.y); u.z = f2b(r.z); u.w = f2b(r.w);
        *(ushort4*)&embB[f][q * 4] = u;
        *(ushort4*)(vb + (size_t)b * 832 + f * 32 + q * 4) = u;
    }
    if (t >= 208 && t < 208 + 96) {  // zero embB rows 26..31
        int o = t - 208;
        *(unsigned int*)&embB[26 + (o >> 4)][(o & 15) * 2] = 0u;
    }
    __syncthreads();

    // ---- P[d][p] = emb[i][d]*emb[j][d] (bf16), p=351 padded 0
    {
        const int d = t & 31, pb = t >> 5;
        const int p0 = pb * 44;
        for (int k = 0; k < 22; ++k) {
            int p = p0 + 2 * k;
            float a  = bf2f(embB[pI[p]][d]) * bf2f(embB[pJ[p]][d]);
            float c2 = (p + 1 < NP_) ? bf2f(embB[pI[p + 1]][d]) * bf2f(embB[pJ[p + 1]][d]) : 0.f;
            *(unsigned int*)&P[d][p] = pk2(a, c2);
        }
        if (t == 0) { float s = blin[0]; for (int f = 0; f < F_; ++f) s += linb[f]; lin[b] = s; }
    }
    __syncthreads();

    // ---- x1 via MFMA: C[d][h] = sum_p P[d][p] * W0s[p][h], M=32, N=128, K=352
    const int wave = t >> 6, lane = t & 63;
    const int lr = lane & 15, lg = lane >> 4;
    const int mt = wave & 1, ntb = (wave >> 1) * 4;
    f32x4 acc[4] = {};
    {
        const unsigned short* Arow = &P[mt * 16 + lr][lg * 8];
        for (int kt = 0; kt < 11; ++kt) {
            bf16x8 af = *(const bf16x8*)(Arow + kt * 32);
#pragma unroll
            for (int n = 0; n < 4; ++n) {
                const unsigned short* bp = W0t + (size_t)((ntb + n) * 16 + lr) * KP_ + kt * 32 + lg * 8;
                bf16x8 bfg = *(const bf16x8*)bp;
                acc[n] = __builtin_amdgcn_mfma_f32_16x16x32_bf16(af, bfg, acc[n], 0, 0, 0);
            }
        }
    }
#pragma unroll
    for (int n = 0; n < 4; ++n) {
        float s = acc[n][0] + acc[n][1] + acc[n][2] + acc[n][3];
        s += __shfl_xor(s, 16, 64);
        s += __shfl_xor(s, 32, 64);
        int h = (ntb + n) * 16 + lr;
        if (lg == 0) cin1t[mt][h] = s;
        int d0 = mt * 16 + lg * 4;
        *(unsigned int*)&x1s[h][d0]     = pk2(acc[n][0], acc[n][1]);
        *(unsigned int*)&x1s[h][d0 + 2] = pk2(acc[n][2], acc[n][3]);
    }
    __syncthreads();

    if (t < 128) cin1[(size_t)b * 128 + t] = cin1t[0][t] + cin1t[1][t];

    // ---- G via MFMA: G[i][j] = sum_d emb[i][d]*x1[j][d], M=32, N=128, K=32
    {
        bf16x8 ea = *(const bf16x8*)&embB[mt * 16 + lr][lg * 8];
#pragma unroll
        for (int n = 0; n < 4; ++n) {
            bf16x8 xb = *(const bf16x8*)&x1s[(ntb + n) * 16 + lr][lg * 8];
            f32x4 g = {};
            g = __builtin_amdgcn_mfma_f32_16x16x32_bf16(ea, xb, g, 0, 0, 0);
            int j = (ntb + n) * 16 + lr;
            int i0 = mt * 16 + lg * 4;
#pragma unroll
            for (int r = 0; r < 4; ++r) {
                int i = i0 + r;
                if (i < F_) G[(size_t)b * 3328 + i * 128 + j] = f2b(g[r]);
            }
        }
    }
}

// ---- K2: bf16 MFMA GEMM v2: 64x128 tile, BK=32, register prefetch ----
// A: M x lda bf16; Bt: N x ldb bf16 (pre-transposed). C: f32 or bf16.
// SPLIT: blockIdx.z selects K-chunk of size kchunk; C partial at z*M*N (f32).
template<bool RELU, bool BIAS, bool OUTB, bool SPLIT>
__global__ __launch_bounds__(256) void gemm2(
    const unsigned short* __restrict__ A,
    const unsigned short* __restrict__ Bt,
    const float* __restrict__ bias,
    void* __restrict__ C,
    int M, int N, int K, int lda, int ldb, int kchunk)
{
    __shared__ __align__(16) unsigned short As[64][40];
    __shared__ __align__(16) unsigned short Bs[128][40];
    const int t = threadIdx.x;
    const int m0 = blockIdx.y * 64, n0 = blockIdx.x * 128;
    const int z = SPLIT ? blockIdx.z : 0;
    const int kbase = z * kchunk;
    const int Keff = min(kchunk, K - kbase);
    const int wave = t >> 6, lane = t & 63;
    const int lr = lane & 15, lg = lane >> 4;
    const int wn = wave * 32;
    const int ar = t >> 2, kg = (t & 3) * 8;

    const unsigned short* aptr  = A  + (size_t)(m0 + ar) * lda + kbase + kg;
    const unsigned short* bptr0 = Bt + (size_t)(n0 + ar) * ldb + kbase + kg;
    const unsigned short* bptr1 = Bt + (size_t)(n0 + 64 + ar) * ldb + kbase + kg;
    const bool bn0 = (n0 + ar) < N, bn1 = (n0 + 64 + ar) < N;

    const uint4 z4 = make_uint4(0u, 0u, 0u, 0u);
    uint4 av, bv0, bv1;
    av  = (kg < Keff)        ? *(const uint4*)(aptr)  : z4;
    bv0 = (bn0 && kg < Keff) ? *(const uint4*)(bptr0) : z4;
    bv1 = (bn1 && kg < Keff) ? *(const uint4*)(bptr1) : z4;

    f32x4 acc[4][2] = {};
    const int nkt = (Keff + 31) >> 5;
    for (int kt = 0; kt < nkt; ++kt) {
        *(uint4*)&As[ar][kg]      = av;
        *(uint4*)&Bs[ar][kg]      = bv0;
        *(uint4*)&Bs[64 + ar][kg] = bv1;
        __syncthreads();
        int kn = (kt + 1) * 32 + kg;
        if (kt + 1 < nkt) {
            av  = (kn < Keff)        ? *(const uint4*)(aptr  + (kt + 1) * 32) : z4;
            bv0 = (bn0 && kn < Keff) ? *(const uint4*)(bptr0 + (kt + 1) * 32) : z4;
            bv1 = (bn1 && kn < Keff) ? *(const uint4*)(bptr1 + (kt + 1) * 32) : z4;
        }
        bf16x8 af[4], bfr[2];
#pragma unroll
        for (int i = 0; i < 4; ++i) af[i]  = *(const bf16x8*)&As[i * 16 + lr][lg * 8];
#pragma unroll
        for (int j = 0; j < 2; ++j) bfr[j] = *(const bf16x8*)&Bs[wn + j * 16 + lr][lg * 8];
#pragma unroll
        for (int i = 0; i < 4; ++i)
#pragma unroll
            for (int j = 0; j < 2; ++j)
                acc[i][j] = __builtin_amdgcn_mfma_f32_16x16x32_bf16(af[i], bfr[j], acc[i][j], 0, 0, 0);
        __syncthreads();
    }

#pragma unroll
    for (int i = 0; i < 4; ++i) {
        int mrow = m0 + i * 16 + lg * 4;
#pragma unroll
        for (int j = 0; j < 2; ++j) {
            int col = n0 + wn + j * 16 + lr;
            if (col >= N) continue;
            float bb = BIAS ? bias[col] : 0.f;
#pragma unroll
            for (int r = 0; r < 4; ++r) {
                float vv = acc[i][j][r] + bb;
                if (RELU) vv = fmaxf(vv, 0.f);
                if (OUTB) ((unsigned short*)C)[(size_t)(mrow + r) * N + col] = f2b(vv);
                else      ((float*)C)[(SPLIT ? (size_t)z * M * N : (size_t)0) + (size_t)(mrow + r) * N + col] = vv;
            }
        }
    }
}

// ---- K3: final concat-dot + sigmoid, one wave per b (sums split-K partials) ----
__global__ __launch_bounds__(256) void k3_final(
    const float* __restrict__ lin,
    const float* __restrict__ cin1,
    const float* __restrict__ cin2p,
    const float* __restrict__ h2,
    const float* __restrict__ dense,
    const float* __restrict__ wout,
    const float* __restrict__ bout,
    float* __restrict__ out)
{
    const int wave = threadIdx.x >> 6, lane = threadIdx.x & 63;
    const int b = blockIdx.x * 4 + wave;
    float s = 0.f;
    for (int o = lane; o < 670; o += 64) {
        float f;
        if (o == 0)        f = lin[b];
        else if (o < 129)  f = cin1[(size_t)b * 128 + (o - 1)];
        else if (o < 257) {
            size_t idx = (size_t)b * 128 + (o - 129);
            f = cin2p[idx] + cin2p[(size_t)B_ * 128 + idx];
        }
        else if (o < 657)  f = h2[(size_t)b * 400 + (o - 257)];
        else               f = dense[(size_t)b * 13 + (o - 657)];
        s = fmaf(f, wout[o], s);
    }
#pragma unroll
    for (int off = 32; off > 0; off >>= 1) s += __shfl_down(s, off, 64);
    if (lane == 0) out[b] = 1.f / (1.f + expf(-(s + bout[0])));
}

extern "C" void kernel_launch(void* const* d_in, const int* in_sizes, int n_in,
                              void* d_out, int out_size, void* d_ws, size_t ws_size,
                              hipStream_t stream) {
    const float* dense  = (const float*)d_in[0];
    const int*   sparse = (const int*)  d_in[1];
    const float* E      = (const float*)d_in[2];
    const float* W0     = (const float*)d_in[3];
    const float* Wc1    = (const float*)d_in[4];
    const float* W1     = (const float*)d_in[5];
    const float* b1     = (const float*)d_in[6];
    const float* W2     = (const float*)d_in[7];
    const float* b2     = (const float*)d_in[8];
    const float* wlin   = (const float*)d_in[9];
    const float* blin   = (const float*)d_in[10];
    const float* wout   = (const float*)d_in[11];
    const float* bout   = (const float*)d_in[12];
    float* out = (float*)d_out;

    char* ws = (char*)d_ws;
    unsigned short* vb    = (unsigned short*)(ws + OFF_VB);
    float*          lin   = (float*)(ws + OFF_LIN);
    float*          cin1  = (float*)(ws + OFF_CIN1);
    float*          cin2p = (float*)(ws + OFF_CIN2P);
    unsigned short* G     = (unsigned short*)(ws + OFF_G);
    unsigned short* h1b   = (unsigned short*)(ws + OFF_H1B);
    float*          h2    = (float*)(ws + OFF_H2);
    unsigned short* W0t   = (unsigned short*)(ws + OFF_W0T);
    unsigned short* Wc1t  = (unsigned short*)(ws + OFF_WC1T);
    unsigned short* W1t   = (unsigned short*)(ws + OFF_W1T);
    unsigned short* W2t   = (unsigned short*)(ws + OFF_W2T);

    k0a_w0<<<(128 * KP_ + 255) / 256, 256, 0, stream>>>(W0, W0t);
    tkern<<<dim3(4, 104), 256, 0, stream>>>(Wc1, Wc1t, 3328, 128);   // (3328,128) -> [128][3328]
    tkern<<<dim3(13, 26), 256, 0, stream>>>(W1, W1t, 832, 400);      // (832,400)  -> [400][832]
    tkern<<<dim3(13, 13), 256, 0, stream>>>(W2, W2t, 400, 400);      // (400,400)  -> [400][400]

    k1_embed_cin<<<B_, 256, 0, stream>>>(sparse, E, W0t, wlin, blin, vb, lin, cin1, G);

    // cin2 partials = G (8192x3328) @ Wc1t^T, split-K=2 (1664 each)
    gemm2<false, false, false, true ><<<dim3(1, 128, 2), 256, 0, stream>>>(G,   Wc1t, nullptr, cin2p, B_, 128, 3328, 3328, 3328, 1664);
    // h1 = relu(v @ W1 + b1), bf16 out
    gemm2<true,  true,  true,  false><<<dim3(4, 128, 1), 256, 0, stream>>>(vb,  W1t,  b1,      h1b,   B_, 400, 832,  832,  832,  832);
    // h2 = relu(h1 @ W2 + b2), f32 out
    gemm2<true,  true,  false, false><<<dim3(4, 128, 1), 256, 0, stream>>>(h1b, W2t,  b2,      h2,    B_, 400, 400,  400,  400,  400);

    k3_final<<<B_ / 4, 256, 0, stream>>>(lin, cin1, cin2p, h2, dense, wout, bout, out);
}

// Round 4
// 561.086 us; speedup vs baseline: 2.2832x; 1.0379x over previous
//
#include <hip/hip_runtime.h>
#include <hip/hip_bf16.h>
#include <math.h>

typedef __attribute__((ext_vector_type(8))) short bf16x8;
typedef __attribute__((ext_vector_type(4))) float f32x4;

#define B_ 8192
#define F_ 26
#define D_ 32
#define V_ 100000
#define NP_ 351
#define KP_ 352

// ---- ws layout (bytes), 16B-aligned ----
static const size_t OFF_VB    = 0;                        // bf16 8192x832   = 13631488
static const size_t OFF_LIN   = 13631488;                 // f32 8192        = 32768
static const size_t OFF_CIN1  = 13664256;                 // f32 8192x128    = 4194304
static const size_t OFF_CIN2P = 17858560;                 // f32 4x8192x128  = 16777216
static const size_t OFF_G     = 34635776;                 // bf16 8192x3328  = 54525952
static const size_t OFF_H1B   = 89161728;                 // bf16 8192x400   = 6553600
static const size_t OFF_H2    = 95715328;                 // f32 8192x400    = 13107200
static const size_t OFF_W0T   = 108822528;                // bf16 128x352    = 90112
static const size_t OFF_WC1T  = 108912640;                // bf16 128x3328   = 851968
static const size_t OFF_W1T   = 109764608;                // bf16 400x832    = 665600
static const size_t OFF_W2T   = 110430208;                // bf16 400x400    = 320000
// total ~105.6 MB

// RNE bf16 (weights only — one-time prep)
static __device__ __forceinline__ unsigned short f2b(float f) {
    unsigned int u = __float_as_uint(f);
    return (unsigned short)((u + 0x7FFF + ((u >> 16) & 1)) >> 16);
}
// truncating bf16 (activations: error budget is huge)
static __device__ __forceinline__ unsigned short f2bt(float f) {
    return (unsigned short)(__float_as_uint(f) >> 16);
}
// pack two truncated bf16 in ONE v_perm_b32: lo16 = hi16(a), hi16 = hi16(b)
static __device__ __forceinline__ unsigned int pk2t(float a, float b) {
    return __builtin_amdgcn_perm(__float_as_uint(b), __float_as_uint(a), 0x07060302u);
}
static __device__ __forceinline__ float bf2f(unsigned short u) {
    return __uint_as_float(((unsigned int)u) << 16);
}

// ======== K0: all weight prep in one dispatch ========
static __device__ __forceinline__ void transpose_body(
    const float* __restrict__ src, unsigned short* __restrict__ dst,
    int K, int N, int bx, int by)
{
    __shared__ float tl[32][33];
    const int lx = threadIdx.x & 31, ly = threadIdx.x >> 5;
    const int n0 = bx * 32, k0 = by * 32;
#pragma unroll
    for (int i = 0; i < 4; ++i) {
        int k = k0 + ly + i * 8, n = n0 + lx;
        if (k < K && n < N) tl[ly + i * 8][lx] = src[(size_t)k * N + n];
    }
    __syncthreads();
#pragma unroll
    for (int i = 0; i < 4; ++i) {
        int n = n0 + ly + i * 8, k = k0 + lx;
        if (k < K && n < N) dst[(size_t)n * K + k] = f2b(tl[lx][ly + i * 8]);
    }
}

__global__ __launch_bounds__(256) void k0_all(
    const float* __restrict__ W0, const float* __restrict__ Wc1,
    const float* __restrict__ W1, const float* __restrict__ W2,
    unsigned short* __restrict__ W0t, unsigned short* __restrict__ Wc1t,
    unsigned short* __restrict__ W1t, unsigned short* __restrict__ W2t)
{
    int bid = blockIdx.x;
    if (bid < 176) {   // W0 symmetrize -> W0t[h][p]
        int g = bid * 256 + threadIdx.x;
        if (g < 128 * KP_) {
            int h = g / KP_, p = g % KP_;
            float w = 0.f;
            if (p < NP_) {
                int i = 0, base = 0;
                while (base + (F_ - i) <= p) { base += F_ - i; ++i; }
                int j = i + (p - base);
                w = W0[(i * F_ + j) * 128 + h];
                if (i != j) w += W0[(j * F_ + i) * 128 + h];
            }
            W0t[g] = f2b(w);
        }
        return;
    }
    bid -= 176;
    const float* src; unsigned short* dst; int K, N, nx;
    if (bid < 416)               { src = Wc1; dst = Wc1t; K = 3328; N = 128; nx = 4; }
    else if ((bid -= 416) < 338) { src = W1;  dst = W1t;  K = 832;  N = 400; nx = 13; }
    else                         { bid -= 338; src = W2; dst = W2t; K = 400; N = 400; nx = 13; }
    transpose_body(src, dst, K, N, bid % nx, bid / nx);
}

// ======== K1: per-b gather, linear, x1 (MFMA), cin1, G (MFMA) ========
__global__ __launch_bounds__(256) void k1_embed_cin(
    const int*   __restrict__ sparse,
    const float* __restrict__ E,
    const unsigned short* __restrict__ W0t,
    const float* __restrict__ wlin,
    const float* __restrict__ blin,
    unsigned short* __restrict__ vb,
    float* __restrict__ lin,
    float* __restrict__ cin1,
    unsigned short* __restrict__ G)
{
    __shared__ __align__(16) unsigned short embB[32][40];
    __shared__ __align__(16) unsigned short P[32][360];
    __shared__ __align__(16) unsigned short x1s[128][40];
    __shared__ float cin1t[2][128];
    __shared__ float linb[F_];
    __shared__ int   idxs[F_];
    __shared__ unsigned char pI[KP_], pJ[KP_];

    const int b = blockIdx.x, t = threadIdx.x;

    if (t < F_) {
        int id = sparse[b * F_ + t];
        idxs[t] = id;
        linb[t] = (float)id * wlin[t];
        int i = t, base = F_ * i - (i * (i - 1)) / 2;
        for (int j = i; j < F_; ++j) { pI[base + j - i] = (unsigned char)i; pJ[base + j - i] = (unsigned char)j; }
    }
    __syncthreads();

    if (t < 208) {  // 26 rows x 8 float4
        int f = t >> 3, q = t & 7;
        float4 r = *(const float4*)(E + ((size_t)f * V_ + idxs[f]) * D_ + q * 4);
        uint2 uu;
        uu.x = pk2t(r.x, r.y);
        uu.y = pk2t(r.z, r.w);
        *(uint2*)&embB[f][q * 4] = uu;
        *(uint2*)(vb + (size_t)b * 832 + f * 32 + q * 4) = uu;
    }
    if (t >= 208 && t < 208 + 96) {  // zero rows 26..31
        int o = t - 208;
        *(unsigned int*)&embB[26 + (o >> 4)][(o & 15) * 2] = 0u;
    }
    __syncthreads();

    // P[d][p] = emb[i][d]*emb[j][d] bf16-trunc, p=351 padded 0
    {
        const int d = t & 31, pb = t >> 5;
        const int p0 = pb * 44;
        for (int k = 0; k < 22; ++k) {
            int p = p0 + 2 * k;
            float a  = bf2f(embB[pI[p]][d]) * bf2f(embB[pJ[p]][d]);
            float c2 = (p + 1 < NP_) ? bf2f(embB[pI[p + 1]][d]) * bf2f(embB[pJ[p + 1]][d]) : 0.f;
            *(unsigned int*)&P[d][p] = pk2t(a, c2);
        }
        if (t == 0) { float s = blin[0]; for (int f = 0; f < F_; ++f) s += linb[f]; lin[b] = s; }
    }
    __syncthreads();

    // x1 via MFMA: C[d][h] = sum_p P[d][p] * W0s[p][h]
    const int wave = t >> 6, lane = t & 63;
    const int lr = lane & 15, lg = lane >> 4;
    const int mt = wave & 1, ntb = (wave >> 1) * 4;
    f32x4 acc[4] = {};
    {
        const unsigned short* Arow = &P[mt * 16 + lr][lg * 8];
        for (int kt = 0; kt < 11; ++kt) {
            bf16x8 af = *(const bf16x8*)(Arow + kt * 32);
#pragma unroll
            for (int n = 0; n < 4; ++n) {
                const unsigned short* bp = W0t + (size_t)((ntb + n) * 16 + lr) * KP_ + kt * 32 + lg * 8;
                bf16x8 bfg = *(const bf16x8*)bp;
                acc[n] = __builtin_amdgcn_mfma_f32_16x16x32_bf16(af, bfg, acc[n], 0, 0, 0);
            }
        }
    }
#pragma unroll
    for (int n = 0; n < 4; ++n) {
        float s = acc[n][0] + acc[n][1] + acc[n][2] + acc[n][3];
        s += __shfl_xor(s, 16, 64);
        s += __shfl_xor(s, 32, 64);
        int h = (ntb + n) * 16 + lr;
        if (lg == 0) cin1t[mt][h] = s;
        int d0 = mt * 16 + lg * 4;
        *(unsigned int*)&x1s[h][d0]     = pk2t(acc[n][0], acc[n][1]);
        *(unsigned int*)&x1s[h][d0 + 2] = pk2t(acc[n][2], acc[n][3]);
    }
    __syncthreads();

    if (t < 128) cin1[(size_t)b * 128 + t] = cin1t[0][t] + cin1t[1][t];

    // G via MFMA: G[i][j] = sum_d emb[i][d]*x1[j][d]
    {
        bf16x8 ea = *(const bf16x8*)&embB[mt * 16 + lr][lg * 8];
#pragma unroll
        for (int n = 0; n < 4; ++n) {
            bf16x8 xb = *(const bf16x8*)&x1s[(ntb + n) * 16 + lr][lg * 8];
            f32x4 g = {};
            g = __builtin_amdgcn_mfma_f32_16x16x32_bf16(ea, xb, g, 0, 0, 0);
            int j = (ntb + n) * 16 + lr;
            int i0 = mt * 16 + lg * 4;
#pragma unroll
            for (int r = 0; r < 4; ++r) {
                int i = i0 + r;
                if (i < F_) G[(size_t)b * 3328 + i * 128 + j] = f2bt(g[r]);
            }
        }
    }
}

// ======== shared GEMM body: 64x128 tile, K = 26*32 = 832 fixed, reg prefetch ========
static __device__ __forceinline__ void gemm_body(
    const unsigned short* __restrict__ A, int lda, int kbase,
    const unsigned short* __restrict__ Bt, int ldb, int N,
    const float* __restrict__ bias, bool relu, bool outb,
    void* __restrict__ C, int ldc, int m0, int n0,
    unsigned short (*As)[40], unsigned short (*Bs)[40])
{
    const int t = threadIdx.x;
    const int wave = t >> 6, lane = t & 63;
    const int lr = lane & 15, lg = lane >> 4;
    const int wn = wave * 32;
    const int ar = t >> 2, kg = (t & 3) * 8;

    const unsigned short* aptr = A  + (size_t)(m0 + ar) * lda + kbase + kg;
    const unsigned short* bp0  = Bt + (size_t)(n0 + ar) * ldb + kbase + kg;
    const unsigned short* bp1  = Bt + (size_t)(n0 + 64 + ar) * ldb + kbase + kg;
    const bool bn0 = (n0 + ar) < N, bn1 = (n0 + 64 + ar) < N;

    const uint4 z4 = make_uint4(0u, 0u, 0u, 0u);
    uint4 av  = *(const uint4*)aptr;
    uint4 bv0 = bn0 ? *(const uint4*)bp0 : z4;
    uint4 bv1 = bn1 ? *(const uint4*)bp1 : z4;

    f32x4 acc[4][2] = {};
    for (int kt = 0; kt < 26; ++kt) {
        *(uint4*)&As[ar][kg]      = av;
        *(uint4*)&Bs[ar][kg]      = bv0;
        *(uint4*)&Bs[64 + ar][kg] = bv1;
        __syncthreads();
        if (kt + 1 < 26) {
            av  = *(const uint4*)(aptr + (kt + 1) * 32);
            bv0 = bn0 ? *(const uint4*)(bp0 + (kt + 1) * 32) : z4;
            bv1 = bn1 ? *(const uint4*)(bp1 + (kt + 1) * 32) : z4;
        }
        bf16x8 af[4], bfr[2];
#pragma unroll
        for (int i = 0; i < 4; ++i) af[i]  = *(const bf16x8*)&As[i * 16 + lr][lg * 8];
#pragma unroll
        for (int j = 0; j < 2; ++j) bfr[j] = *(const bf16x8*)&Bs[wn + j * 16 + lr][lg * 8];
#pragma unroll
        for (int i = 0; i < 4; ++i)
#pragma unroll
            for (int j = 0; j < 2; ++j)
                acc[i][j] = __builtin_amdgcn_mfma_f32_16x16x32_bf16(af[i], bfr[j], acc[i][j], 0, 0, 0);
        __syncthreads();
    }
#pragma unroll
    for (int i = 0; i < 4; ++i) {
        int mrow = m0 + i * 16 + lg * 4;
#pragma unroll
        for (int j = 0; j < 2; ++j) {
            int col = n0 + wn + j * 16 + lr;
            if (col >= N) continue;
            float bb = bias ? bias[col] : 0.f;
#pragma unroll
            for (int r = 0; r < 4; ++r) {
                float vv = acc[i][j][r] + bb;
                if (relu) vv = fmaxf(vv, 0.f);
                if (outb) ((unsigned short*)C)[(size_t)(mrow + r) * ldc + col] = f2bt(vv);
                else      ((float*)C)[(size_t)(mrow + r) * ldc + col] = vv;
            }
        }
    }
}

// K2a: h1 (z=0) and cin2 split-K=4 (z=1) in one dispatch — both are 26-kt loops
__global__ __launch_bounds__(256) void k2_h1_cin2(
    const unsigned short* __restrict__ vb, const unsigned short* __restrict__ W1t,
    const float* __restrict__ b1, unsigned short* __restrict__ h1b,
    const unsigned short* __restrict__ G, const unsigned short* __restrict__ Wc1t,
    float* __restrict__ cin2p)
{
    __shared__ __align__(16) unsigned short As[64][40];
    __shared__ __align__(16) unsigned short Bs[128][40];
    const int m0 = blockIdx.y * 64;
    if (blockIdx.z == 0) {
        gemm_body(vb, 832, 0, W1t, 832, 400, b1, true, true, h1b, 400,
                  m0, blockIdx.x * 128, As, Bs);
    } else {
        float* Cp = cin2p + (size_t)blockIdx.x * B_ * 128;
        gemm_body(G, 3328, blockIdx.x * 832, Wc1t, 3328, 128, nullptr, false, false, Cp, 128,
                  m0, 0, As, Bs);
    }
}

// K2b: h2 = relu(h1 @ W2 + b2), K=400 (13 kt with guards)
__global__ __launch_bounds__(256) void k2_h2(
    const unsigned short* __restrict__ A, const unsigned short* __restrict__ Bt,
    const float* __restrict__ bias, float* __restrict__ C)
{
    __shared__ __align__(16) unsigned short As[64][40];
    __shared__ __align__(16) unsigned short Bs[128][40];
    const int t = threadIdx.x;
    const int m0 = blockIdx.y * 64, n0 = blockIdx.x * 128;
    const int N = 400, K = 400, ld = 400;
    const int wave = t >> 6, lane = t & 63;
    const int lr = lane & 15, lg = lane >> 4;
    const int wn = wave * 32;
    const int ar = t >> 2, kg = (t & 3) * 8;

    const unsigned short* aptr = A  + (size_t)(m0 + ar) * ld + kg;
    const unsigned short* bp0  = Bt + (size_t)(n0 + ar) * ld + kg;
    const unsigned short* bp1  = Bt + (size_t)(n0 + 64 + ar) * ld + kg;
    const bool bn0 = (n0 + ar) < N, bn1 = (n0 + 64 + ar) < N;
    const uint4 z4 = make_uint4(0u, 0u, 0u, 0u);
    uint4 av, bv0, bv1;
    av  = (kg < K)        ? *(const uint4*)aptr : z4;
    bv0 = (bn0 && kg < K) ? *(const uint4*)bp0  : z4;
    bv1 = (bn1 && kg < K) ? *(const uint4*)bp1  : z4;

    f32x4 acc[4][2] = {};
    const int nkt = 13;
    for (int kt = 0; kt < nkt; ++kt) {
        *(uint4*)&As[ar][kg]      = av;
        *(uint4*)&Bs[ar][kg]      = bv0;
        *(uint4*)&Bs[64 + ar][kg] = bv1;
        __syncthreads();
        int kn = (kt + 1) * 32 + kg;
        if (kt + 1 < nkt) {
            av  = (kn < K)        ? *(const uint4*)(aptr + (kt + 1) * 32) : z4;
            bv0 = (bn0 && kn < K) ? *(const uint4*)(bp0  + (kt + 1) * 32) : z4;
            bv1 = (bn1 && kn < K) ? *(const uint4*)(bp1  + (kt + 1) * 32) : z4;
        }
        bf16x8 af[4], bfr[2];
#pragma unroll
        for (int i = 0; i < 4; ++i) af[i]  = *(const bf16x8*)&As[i * 16 + lr][lg * 8];
#pragma unroll
        for (int j = 0; j < 2; ++j) bfr[j] = *(const bf16x8*)&Bs[wn + j * 16 + lr][lg * 8];
#pragma unroll
        for (int i = 0; i < 4; ++i)
#pragma unroll
            for (int j = 0; j < 2; ++j)
                acc[i][j] = __builtin_amdgcn_mfma_f32_16x16x32_bf16(af[i], bfr[j], acc[i][j], 0, 0, 0);
        __syncthreads();
    }
#pragma unroll
    for (int i = 0; i < 4; ++i) {
        int mrow = m0 + i * 16 + lg * 4;
#pragma unroll
        for (int j = 0; j < 2; ++j) {
            int col = n0 + wn + j * 16 + lr;
            if (col >= N) continue;
            float bb = bias[col];
#pragma unroll
            for (int r = 0; r < 4; ++r)
                C[(size_t)(mrow + r) * N + col] = fmaxf(acc[i][j][r] + bb, 0.f);
        }
    }
}

// ======== K3: final concat-dot + sigmoid (sums 4 cin2 partials) ========
__global__ __launch_bounds__(256) void k3_final(
    const float* __restrict__ lin,
    const float* __restrict__ cin1,
    const float* __restrict__ cin2p,
    const float* __restrict__ h2,
    const float* __restrict__ dense,
    const float* __restrict__ wout,
    const float* __restrict__ bout,
    float* __restrict__ out)
{
    const int wave = threadIdx.x >> 6, lane = threadIdx.x & 63;
    const int b = blockIdx.x * 4 + wave;
    const size_t S = (size_t)B_ * 128;
    float s = 0.f;
    for (int o = lane; o < 670; o += 64) {
        float f;
        if (o == 0)        f = lin[b];
        else if (o < 129)  f = cin1[(size_t)b * 128 + (o - 1)];
        else if (o < 257) {
            size_t idx = (size_t)b * 128 + (o - 129);
            f = (cin2p[idx] + cin2p[S + idx]) + (cin2p[2 * S + idx] + cin2p[3 * S + idx]);
        }
        else if (o < 657)  f = h2[(size_t)b * 400 + (o - 257)];
        else               f = dense[(size_t)b * 13 + (o - 657)];
        s = fmaf(f, wout[o], s);
    }
#pragma unroll
    for (int off = 32; off > 0; off >>= 1) s += __shfl_down(s, off, 64);
    if (lane == 0) out[b] = 1.f / (1.f + expf(-(s + bout[0])));
}

extern "C" void kernel_launch(void* const* d_in, const int* in_sizes, int n_in,
                              void* d_out, int out_size, void* d_ws, size_t ws_size,
                              hipStream_t stream) {
    const float* dense  = (const float*)d_in[0];
    const int*   sparse = (const int*)  d_in[1];
    const float* E      = (const float*)d_in[2];
    const float* W0     = (const float*)d_in[3];
    const float* Wc1    = (const float*)d_in[4];
    const float* W1     = (const float*)d_in[5];
    const float* b1     = (const float*)d_in[6];
    const float* W2     = (const float*)d_in[7];
    const float* b2     = (const float*)d_in[8];
    const float* wlin   = (const float*)d_in[9];
    const float* blin   = (const float*)d_in[10];
    const float* wout   = (const float*)d_in[11];
    const float* bout   = (const float*)d_in[12];
    float* out = (float*)d_out;

    char* ws = (char*)d_ws;
    unsigned short* vb    = (unsigned short*)(ws + OFF_VB);
    float*          lin   = (float*)(ws + OFF_LIN);
    float*          cin1  = (float*)(ws + OFF_CIN1);
    float*          cin2p = (float*)(ws + OFF_CIN2P);
    unsigned short* G     = (unsigned short*)(ws + OFF_G);
    unsigned short* h1b   = (unsigned short*)(ws + OFF_H1B);
    float*          h2    = (float*)(ws + OFF_H2);
    unsigned short* W0t   = (unsigned short*)(ws + OFF_W0T);
    unsigned short* Wc1t  = (unsigned short*)(ws + OFF_WC1T);
    unsigned short* W1t   = (unsigned short*)(ws + OFF_W1T);
    unsigned short* W2t   = (unsigned short*)(ws + OFF_W2T);

    k0_all<<<176 + 416 + 338 + 169, 256, 0, stream>>>(W0, Wc1, W1, W2, W0t, Wc1t, W1t, W2t);
    k1_embed_cin<<<B_, 256, 0, stream>>>(sparse, E, W0t, wlin, blin, vb, lin, cin1, G);
    // z=0: h1 (4 n-blocks x 128 m-blocks); z=1: cin2 split-K (4 chunks x 128 m-blocks)
    k2_h1_cin2<<<dim3(4, 128, 2), 256, 0, stream>>>(vb, W1t, b1, h1b, G, Wc1t, cin2p);
    k2_h2<<<dim3(4, 128), 256, 0, stream>>>(h1b, W2t, b2, h2);
    k3_final<<<B_ / 4, 256, 0, stream>>>(lin, cin1, cin2p, h2, dense, wout, bout, out);
}

// Round 5
// 534.851 us; speedup vs baseline: 2.3952x; 1.0491x over previous
//
#include <hip/hip_runtime.h>
#include <hip/hip_bf16.h>
#include <math.h>

typedef __attribute__((ext_vector_type(8))) short bf16x8;
typedef __attribute__((ext_vector_type(4))) float f32x4;

#define B_ 8192
#define F_ 26
#define D_ 32
#define V_ 100000
#define NP_ 351
#define KP_ 352

// ---- ws layout (bytes), 16B-aligned ----
static const size_t OFF_VB   = 0;             // bf16 8192x832  = 13631488
static const size_t OFF_FD0  = 13631488;      // f32 8192       = 32768  (lin+cin1 partial dot)
static const size_t OFF_PDC2 = 13664256;      // f32 4x8192     = 131072 (cin2 split-K partial dots)
static const size_t OFF_PDH2 = 13795328;      // f32 4x8192     = 131072 (h2 col-chunk partial dots)
static const size_t OFF_G    = 13926400;      // bf16 8192x3328 = 54525952
static const size_t OFF_H1B  = 68452352;      // bf16 8192x400  = 6553600
static const size_t OFF_W0T  = 75005952;      // bf16 128x352   = 90112
static const size_t OFF_WC1T = 75096064;      // bf16 128x3328  = 851968
static const size_t OFF_W1T  = 75948032;      // bf16 400x832   = 665600
static const size_t OFF_W2T  = 76613632;      // bf16 400x400   = 320000
// total ~73.4 MB

// RNE bf16 (weights, one-time)
static __device__ __forceinline__ unsigned short f2b(float f) {
    unsigned int u = __float_as_uint(f);
    return (unsigned short)((u + 0x7FFF + ((u >> 16) & 1)) >> 16);
}
// truncating bf16 (activations)
static __device__ __forceinline__ unsigned short f2bt(float f) {
    return (unsigned short)(__float_as_uint(f) >> 16);
}
// pack two truncated bf16 in one v_perm_b32
static __device__ __forceinline__ unsigned int pk2t(float a, float b) {
    return __builtin_amdgcn_perm(__float_as_uint(b), __float_as_uint(a), 0x07060302u);
}
static __device__ __forceinline__ float bf2f(unsigned short u) {
    return __uint_as_float(((unsigned int)u) << 16);
}

// ======== K0: all weight prep in one dispatch ========
static __device__ __forceinline__ void transpose_body(
    const float* __restrict__ src, unsigned short* __restrict__ dst,
    int K, int N, int bx, int by)
{
    __shared__ float tl[32][33];
    const int lx = threadIdx.x & 31, ly = threadIdx.x >> 5;
    const int n0 = bx * 32, k0 = by * 32;
#pragma unroll
    for (int i = 0; i < 4; ++i) {
        int k = k0 + ly + i * 8, n = n0 + lx;
        if (k < K && n < N) tl[ly + i * 8][lx] = src[(size_t)k * N + n];
    }
    __syncthreads();
#pragma unroll
    for (int i = 0; i < 4; ++i) {
        int n = n0 + ly + i * 8, k = k0 + lx;
        if (k < K && n < N) dst[(size_t)n * K + k] = f2b(tl[lx][ly + i * 8]);
    }
}

__global__ __launch_bounds__(256) void k0_all(
    const float* __restrict__ W0, const float* __restrict__ Wc1,
    const float* __restrict__ W1, const float* __restrict__ W2,
    unsigned short* __restrict__ W0t, unsigned short* __restrict__ Wc1t,
    unsigned short* __restrict__ W1t, unsigned short* __restrict__ W2t)
{
    int bid = blockIdx.x;
    if (bid < 176) {   // W0 symmetrize -> W0t[h][p]
        int g = bid * 256 + threadIdx.x;
        if (g < 128 * KP_) {
            int h = g / KP_, p = g % KP_;
            float w = 0.f;
            if (p < NP_) {
                int i = 0, base = 0;
                while (base + (F_ - i) <= p) { base += F_ - i; ++i; }
                int j = i + (p - base);
                w = W0[(i * F_ + j) * 128 + h];
                if (i != j) w += W0[(j * F_ + i) * 128 + h];
            }
            W0t[g] = f2b(w);
        }
        return;
    }
    bid -= 176;
    const float* src; unsigned short* dst; int K, N, nx;
    if (bid < 416)               { src = Wc1; dst = Wc1t; K = 3328; N = 128; nx = 4; }
    else if ((bid -= 416) < 338) { src = W1;  dst = W1t;  K = 832;  N = 400; nx = 13; }
    else                         { bid -= 338; src = W2; dst = W2t; K = 400; N = 400; nx = 13; }
    transpose_body(src, dst, K, N, bid % nx, bid / nx);
}

// ======== K1: 2 batch-elements per block: gather, lin+cin1 dot, x1, G ========
__global__ __launch_bounds__(256) void k1_embed_cin(
    const int*   __restrict__ sparse,
    const float* __restrict__ E,
    const unsigned short* __restrict__ W0t,
    const float* __restrict__ wlin,
    const float* __restrict__ blin,
    const float* __restrict__ wout,
    unsigned short* __restrict__ vb,
    float* __restrict__ fdot0,
    unsigned short* __restrict__ G)
{
    __shared__ __align__(16) unsigned short embB[64][40];   // rows 0-31: b0 (26..31 zero), 32-63: b1
    __shared__ __align__(16) unsigned short Pbuf[64 * 360]; // P[bb*32+d][p]; later overlaid by x1s[bb][h][40]
    __shared__ float wdot[4];
    __shared__ float linv[52];
    __shared__ int   idxs[52];
    __shared__ unsigned char pI[NP_], pJ[NP_];

    const int b0 = blockIdx.x * 2, t = threadIdx.x;

    if (t < 52) {
        int bb = t >= 26 ? 1 : 0, ff = t - bb * 26;
        int id = sparse[(b0 + bb) * F_ + ff];
        idxs[t] = id;
        linv[t] = (float)id * wlin[ff];
    }
    if (t < F_) {
        int i = t, base = F_ * i - (i * (i - 1)) / 2;
        for (int j = i; j < F_; ++j) { pI[base + j - i] = (unsigned char)i; pJ[base + j - i] = (unsigned char)j; }
    }
    __syncthreads();

    // gather 52 rows x 8 float4
    for (int r = t; r < 416; r += 256) {
        int f = r >> 3, q = r & 7;
        int bb = f >= 26 ? 1 : 0, ff = f - bb * 26;
        float4 v4 = *(const float4*)(E + ((size_t)ff * V_ + idxs[f]) * D_ + q * 4);
        uint2 uu; uu.x = pk2t(v4.x, v4.y); uu.y = pk2t(v4.z, v4.w);
        *(uint2*)&embB[bb * 32 + ff][q * 4] = uu;
        *(uint2*)(vb + (size_t)(b0 + bb) * 832 + ff * 32 + q * 4) = uu;
    }
    if (t < 192) {  // zero rows 26..31 & 58..63
        int row = t >> 4, bb = row >= 6 ? 1 : 0, rr = row - bb * 6;
        *(unsigned int*)&embB[bb * 32 + 26 + rr][(t & 15) * 2] = 0u;
    }
    __syncthreads();

    // P[bb*32+d][p] = emb[i][d]*emb[j][d] bf16-trunc
    {
        const int d = t & 31, sub = t >> 5;
        const int bb = sub & 1, pb = sub >> 1;
        const int e0 = bb * 32;
        const int p0 = pb * 88;
        unsigned short* Prow = &Pbuf[(e0 + d) * 360];
        for (int k = 0; k < 44; ++k) {
            int p = p0 + 2 * k;
            float a = bf2f(embB[e0 + pI[p]][d]) * bf2f(embB[e0 + pJ[p]][d]);
            float c = (p + 1 < NP_) ? bf2f(embB[e0 + pI[p + 1]][d]) * bf2f(embB[e0 + pJ[p + 1]][d]) : 0.f;
            *(unsigned int*)&Prow[p] = pk2t(a, c);
        }
    }
    __syncthreads();

    // x1 MFMA: per wave: bb = wave&1 (M rows bb*32..+31), h-range (wave>>1)*64..+63
    const int wave = t >> 6, lane = t & 63;
    const int lr = lane & 15, lg = lane >> 4;
    const int bb = wave & 1;
    const int h0 = (wave >> 1) * 64;
    f32x4 acc[2][4] = {};
    {
        const unsigned short* Ab = &Pbuf[(bb * 32 + lr) * 360];
        const unsigned short* Bb = W0t + (size_t)(h0 + lr) * KP_ + lg * 8;
        for (int kt = 0; kt < 11; ++kt) {
            const int ko = kt * 32 + lg * 8;
            bf16x8 a0 = *(const bf16x8*)(Ab + ko);
            bf16x8 a1 = *(const bf16x8*)(Ab + 16 * 360 + ko);
#pragma unroll
            for (int n = 0; n < 4; ++n) {
                bf16x8 bw = *(const bf16x8*)(Bb + (size_t)(n * 16) * KP_ + kt * 32);
                acc[0][n] = __builtin_amdgcn_mfma_f32_16x16x32_bf16(a0, bw, acc[0][n], 0, 0, 0);
                acc[1][n] = __builtin_amdgcn_mfma_f32_16x16x32_bf16(a1, bw, acc[1][n], 0, 0, 0);
            }
        }
    }

    // cin1 dot: s[h] = sum_d x1, dot with wout[1+h]
    float dotv = 0.f;
#pragma unroll
    for (int n = 0; n < 4; ++n) {
        float s = acc[0][n][0] + acc[0][n][1] + acc[0][n][2] + acc[0][n][3]
                + acc[1][n][0] + acc[1][n][1] + acc[1][n][2] + acc[1][n][3];
        s += __shfl_xor(s, 16, 64);
        s += __shfl_xor(s, 32, 64);
        if (lg == 0) dotv += s * wout[1 + h0 + n * 16 + lr];
    }
#pragma unroll
    for (int off = 1; off <= 32; off <<= 1) dotv += __shfl_xor(dotv, off, 64);
    if (lane == 0) wdot[wave] = dotv;
    __syncthreads();   // all P reads done; wdot visible

    // x1 -> LDS overlay (x1s[bb][h][40] over Pbuf)
#pragma unroll
    for (int n = 0; n < 4; ++n) {
        const int base = ((bb << 7) + h0 + n * 16 + lr) * 40;
#pragma unroll
        for (int mi = 0; mi < 2; ++mi) {
            *(unsigned int*)&Pbuf[base + mi * 16 + lg * 4]     = pk2t(acc[mi][n][0], acc[mi][n][1]);
            *(unsigned int*)&Pbuf[base + mi * 16 + lg * 4 + 2] = pk2t(acc[mi][n][2], acc[mi][n][3]);
        }
    }
    __syncthreads();

    if (t < 2) {
        float s = blin[0];
        for (int f = 0; f < F_; ++f) s += linv[t * 26 + f];
        fdot0[b0 + t] = s * wout[0] + wdot[t] + wdot[t + 2];
    }

    // G MFMA: G[b][i][j] = sum_d emb[i][d]*x1[j][d]
    {
        bf16x8 ga0 = *(const bf16x8*)&embB[bb * 32 + lr][lg * 8];
        bf16x8 ga1 = *(const bf16x8*)&embB[bb * 32 + 16 + lr][lg * 8];
        unsigned short* Gb = G + (size_t)(b0 + bb) * 3328;
#pragma unroll
        for (int n = 0; n < 4; ++n) {
            const int j = h0 + n * 16 + lr;
            bf16x8 xb = *(const bf16x8*)&Pbuf[((bb << 7) + j) * 40 + lg * 8];
            f32x4 g0 = {}, g1 = {};
            g0 = __builtin_amdgcn_mfma_f32_16x16x32_bf16(ga0, xb, g0, 0, 0, 0);
            g1 = __builtin_amdgcn_mfma_f32_16x16x32_bf16(ga1, xb, g1, 0, 0, 0);
#pragma unroll
            for (int r = 0; r < 4; ++r) {
                int i0 = lg * 4 + r;
                Gb[i0 * 128 + j] = f2bt(g0[r]);
                int i1 = 16 + lg * 4 + r;
                if (i1 < F_) Gb[i1 * 128 + j] = f2bt(g1[r]);
            }
        }
    }
}

// ======== GEMM core: 64x128 tile, BK=32, reg prefetch; acc returned ========
static __device__ __forceinline__ void gemm_core(
    const unsigned short* __restrict__ A, int lda,
    const unsigned short* __restrict__ Bt, int ldb, int N,
    int m0, int n0, int kbase, int kend,
    unsigned short (*As)[40], unsigned short (*Bs)[40],
    f32x4 (*acc)[2])
{
    const int t = threadIdx.x;
    const int wave = t >> 6, lane = t & 63;
    const int lr = lane & 15, lg = lane >> 4;
    const int wn = wave * 32;
    const int ar = t >> 2, kg = (t & 3) * 8;

    const unsigned short* aptr = A  + (size_t)(m0 + ar) * lda + kbase + kg;
    const unsigned short* bp0  = Bt + (size_t)(n0 + ar) * ldb + kbase + kg;
    const unsigned short* bp1  = Bt + (size_t)(n0 + 64 + ar) * ldb + kbase + kg;
    const bool bn0 = (n0 + ar) < N, bn1 = (n0 + 64 + ar) < N;
    const uint4 z4 = make_uint4(0u, 0u, 0u, 0u);
    const int nkt = (kend - kbase + 31) >> 5;
    uint4 av, bv0, bv1;
    {
        int k = kbase + kg;
        av  = (k < kend)        ? *(const uint4*)aptr : z4;
        bv0 = (bn0 && k < kend) ? *(const uint4*)bp0  : z4;
        bv1 = (bn1 && k < kend) ? *(const uint4*)bp1  : z4;
    }
    for (int kt = 0; kt < nkt; ++kt) {
        *(uint4*)&As[ar][kg]      = av;
        *(uint4*)&Bs[ar][kg]      = bv0;
        *(uint4*)&Bs[64 + ar][kg] = bv1;
        __syncthreads();
        if (kt + 1 < nkt) {
            int kn = kbase + (kt + 1) * 32 + kg;
            av  = (kn < kend)        ? *(const uint4*)(aptr + (kt + 1) * 32) : z4;
            bv0 = (bn0 && kn < kend) ? *(const uint4*)(bp0  + (kt + 1) * 32) : z4;
            bv1 = (bn1 && kn < kend) ? *(const uint4*)(bp1  + (kt + 1) * 32) : z4;
        }
        bf16x8 af[4], bfr[2];
#pragma unroll
        for (int i = 0; i < 4; ++i) af[i]  = *(const bf16x8*)&As[i * 16 + lr][lg * 8];
#pragma unroll
        for (int j = 0; j < 2; ++j) bfr[j] = *(const bf16x8*)&Bs[wn + j * 16 + lr][lg * 8];
#pragma unroll
        for (int i = 0; i < 4; ++i)
#pragma unroll
            for (int j = 0; j < 2; ++j)
                acc[i][j] = __builtin_amdgcn_mfma_f32_16x16x32_bf16(af[i], bfr[j], acc[i][j], 0, 0, 0);
        __syncthreads();
    }
}

// K2a: z=0 -> h1 = relu(vb@W1+b1) (bf16 out); z=1 -> cin2 split-K partial dots
__global__ __launch_bounds__(256) void k2_h1_cin2(
    const unsigned short* __restrict__ vb, const unsigned short* __restrict__ W1t,
    const float* __restrict__ b1, unsigned short* __restrict__ h1b,
    const unsigned short* __restrict__ G, const unsigned short* __restrict__ Wc1t,
    const float* __restrict__ wout, float* __restrict__ pdc2)
{
    __shared__ __align__(16) unsigned short As[64][40];
    __shared__ __align__(16) unsigned short Bs[128][40];
    __shared__ float red[4][64];
    const int t = threadIdx.x;
    const int wave = t >> 6, lane = t & 63;
    const int lr = lane & 15, lg = lane >> 4;
    const int m0 = blockIdx.y * 64;
    f32x4 acc[4][2] = {};

    if (blockIdx.z == 0) {
        const int n0 = blockIdx.x * 128;
        gemm_core(vb, 832, W1t, 832, 400, m0, n0, 0, 832, As, Bs, acc);
#pragma unroll
        for (int i = 0; i < 4; ++i) {
            int mrow = m0 + i * 16 + lg * 4;
#pragma unroll
            for (int j = 0; j < 2; ++j) {
                int col = n0 + wave * 32 + j * 16 + lr;
                if (col >= 400) continue;
                float bb = b1[col];
#pragma unroll
                for (int r = 0; r < 4; ++r)
                    h1b[(size_t)(mrow + r) * 400 + col] = f2bt(fmaxf(acc[i][j][r] + bb, 0.f));
            }
        }
    } else {
        const int chunk = blockIdx.x;
        gemm_core(G, 3328, Wc1t, 3328, 128, m0, 0, chunk * 832, chunk * 832 + 832, As, Bs, acc);
        float v[4][4];
#pragma unroll
        for (int i = 0; i < 4; ++i)
#pragma unroll
            for (int r = 0; r < 4; ++r) {
                float s = 0.f;
#pragma unroll
                for (int j = 0; j < 2; ++j)
                    s = fmaf(acc[i][j][r], wout[129 + wave * 32 + j * 16 + lr], s);
#pragma unroll
                for (int off = 1; off <= 8; off <<= 1) s += __shfl_xor(s, off, 64);
                v[i][r] = s;
            }
        if (lr == 0) {
#pragma unroll
            for (int i = 0; i < 4; ++i)
#pragma unroll
                for (int r = 0; r < 4; ++r) red[wave][i * 16 + lg * 4 + r] = v[i][r];
        }
        __syncthreads();
        if (t < 64) pdc2[(size_t)chunk * B_ + m0 + t] = red[0][t] + red[1][t] + red[2][t] + red[3][t];
    }
}

// K2b: h2 never materialized — bias+relu+dot(wout) -> pdh2[nb][b]
__global__ __launch_bounds__(256) void k2_h2(
    const unsigned short* __restrict__ h1b, const unsigned short* __restrict__ W2t,
    const float* __restrict__ b2, const float* __restrict__ wout,
    float* __restrict__ pdh2)
{
    __shared__ __align__(16) unsigned short As[64][40];
    __shared__ __align__(16) unsigned short Bs[128][40];
    __shared__ float red[4][64];
    const int t = threadIdx.x;
    const int wave = t >> 6, lane = t & 63;
    const int lr = lane & 15, lg = lane >> 4;
    const int m0 = blockIdx.y * 64, n0 = blockIdx.x * 128;
    f32x4 acc[4][2] = {};
    gemm_core(h1b, 400, W2t, 400, 400, m0, n0, 0, 400, As, Bs, acc);
    float v[4][4];
#pragma unroll
    for (int i = 0; i < 4; ++i)
#pragma unroll
        for (int r = 0; r < 4; ++r) {
            float s = 0.f;
#pragma unroll
            for (int j = 0; j < 2; ++j) {
                int col = n0 + wave * 32 + j * 16 + lr;
                if (col < 400)
                    s = fmaf(fmaxf(acc[i][j][r] + b2[col], 0.f), wout[257 + col], s);
            }
#pragma unroll
            for (int off = 1; off <= 8; off <<= 1) s += __shfl_xor(s, off, 64);
            v[i][r] = s;
        }
    if (lr == 0) {
#pragma unroll
        for (int i = 0; i < 4; ++i)
#pragma unroll
            for (int r = 0; r < 4; ++r) red[wave][i * 16 + lg * 4 + r] = v[i][r];
    }
    __syncthreads();
    if (t < 64) pdh2[(size_t)blockIdx.x * B_ + m0 + t] = red[0][t] + red[1][t] + red[2][t] + red[3][t];
}

// ======== K3: sum partials + dense dot + sigmoid ========
__global__ __launch_bounds__(256) void k3_final(
    const float* __restrict__ fdot0,
    const float* __restrict__ pdc2,
    const float* __restrict__ pdh2,
    const float* __restrict__ dense,
    const float* __restrict__ wout,
    const float* __restrict__ bout,
    float* __restrict__ out)
{
    const int b = blockIdx.x * 256 + threadIdx.x;
    float s = fdot0[b];
#pragma unroll
    for (int z = 0; z < 4; ++z) s += pdc2[(size_t)z * B_ + b];
#pragma unroll
    for (int z = 0; z < 4; ++z) s += pdh2[(size_t)z * B_ + b];
#pragma unroll
    for (int q = 0; q < 13; ++q) s = fmaf(dense[(size_t)b * 13 + q], wout[657 + q], s);
    out[b] = 1.f / (1.f + expf(-(s + bout[0])));
}

extern "C" void kernel_launch(void* const* d_in, const int* in_sizes, int n_in,
                              void* d_out, int out_size, void* d_ws, size_t ws_size,
                              hipStream_t stream) {
    const float* dense  = (const float*)d_in[0];
    const int*   sparse = (const int*)  d_in[1];
    const float* E      = (const float*)d_in[2];
    const float* W0     = (const float*)d_in[3];
    const float* Wc1    = (const float*)d_in[4];
    const float* W1     = (const float*)d_in[5];
    const float* b1     = (const float*)d_in[6];
    const float* W2     = (const float*)d_in[7];
    const float* b2     = (const float*)d_in[8];
    const float* wlin   = (const float*)d_in[9];
    const float* blin   = (const float*)d_in[10];
    const float* wout   = (const float*)d_in[11];
    const float* bout   = (const float*)d_in[12];
    float* out = (float*)d_out;

    char* ws = (char*)d_ws;
    unsigned short* vb    = (unsigned short*)(ws + OFF_VB);
    float*          fdot0 = (float*)(ws + OFF_FD0);
    float*          pdc2  = (float*)(ws + OFF_PDC2);
    float*          pdh2  = (float*)(ws + OFF_PDH2);
    unsigned short* G     = (unsigned short*)(ws + OFF_G);
    unsigned short* h1b   = (unsigned short*)(ws + OFF_H1B);
    unsigned short* W0t   = (unsigned short*)(ws + OFF_W0T);
    unsigned short* Wc1t  = (unsigned short*)(ws + OFF_WC1T);
    unsigned short* W1t   = (unsigned short*)(ws + OFF_W1T);
    unsigned short* W2t   = (unsigned short*)(ws + OFF_W2T);

    k0_all<<<176 + 416 + 338 + 169, 256, 0, stream>>>(W0, Wc1, W1, W2, W0t, Wc1t, W1t, W2t);
    k1_embed_cin<<<B_ / 2, 256, 0, stream>>>(sparse, E, W0t, wlin, blin, wout, vb, fdot0, G);
    k2_h1_cin2<<<dim3(4, 128, 2), 256, 0, stream>>>(vb, W1t, b1, h1b, G, Wc1t, wout, pdc2);
    k2_h2<<<dim3(4, 128), 256, 0, stream>>>(h1b, W2t, b2, wout, pdh2);
    k3_final<<<B_ / 256, 256, 0, stream>>>(fdot0, pdc2, pdh2, dense, wout, bout, out);
}

// Round 6
// 525.996 us; speedup vs baseline: 2.4355x; 1.0168x over previous
//
#include <hip/hip_runtime.h>
#include <hip/hip_bf16.h>
#include <math.h>

typedef __attribute__((ext_vector_type(8))) short bf16x8;
typedef __attribute__((ext_vector_type(4))) float f32x4;

#define B_ 8192
#define F_ 26
#define D_ 32
#define V_ 100000
#define NP_ 351
#define KP_ 352

// ---- ws layout (bytes), 16B-aligned ----
static const size_t OFF_VB   = 0;             // bf16 8192x832  = 13631488
static const size_t OFF_FD0  = 13631488;      // f32 8192       = 32768  (lin+cin1+cin2 partial dot)
static const size_t OFF_PDH2 = 13664256;      // f32 4x8192     = 131072 (h2 col-chunk partial dots)
static const size_t OFF_H1B  = 13795328;      // bf16 8192x400  = 6553600
static const size_t OFF_W0T  = 20348928;      // bf16 128x352   = 90112
static const size_t OFF_W1T  = 20439040;      // bf16 400x832   = 665600
static const size_t OFF_W2T  = 21104640;      // bf16 400x400   = 320000
static const size_t OFF_MWT  = 21424640;      // f32 128x32     = 16384  (Mw transposed+padded)
// total ~20.4 MB

// RNE bf16 (weights, one-time)
static __device__ __forceinline__ unsigned short f2b(float f) {
    unsigned int u = __float_as_uint(f);
    return (unsigned short)((u + 0x7FFF + ((u >> 16) & 1)) >> 16);
}
// truncating bf16 (activations)
static __device__ __forceinline__ unsigned short f2bt(float f) {
    return (unsigned short)(__float_as_uint(f) >> 16);
}
// pack two truncated bf16 in one v_perm_b32
static __device__ __forceinline__ unsigned int pk2t(float a, float b) {
    return __builtin_amdgcn_perm(__float_as_uint(b), __float_as_uint(a), 0x07060302u);
}
static __device__ __forceinline__ float bf2f(unsigned short u) {
    return __uint_as_float(((unsigned int)u) << 16);
}

// ======== K0: all weight prep in one dispatch ========
static __device__ __forceinline__ void transpose_body(
    const float* __restrict__ src, unsigned short* __restrict__ dst,
    int K, int N, int bx, int by)
{
    __shared__ float tl[32][33];
    const int lx = threadIdx.x & 31, ly = threadIdx.x >> 5;
    const int n0 = bx * 32, k0 = by * 32;
#pragma unroll
    for (int i = 0; i < 4; ++i) {
        int k = k0 + ly + i * 8, n = n0 + lx;
        if (k < K && n < N) tl[ly + i * 8][lx] = src[(size_t)k * N + n];
    }
    __syncthreads();
#pragma unroll
    for (int i = 0; i < 4; ++i) {
        int n = n0 + ly + i * 8, k = k0 + lx;
        if (k < K && n < N) dst[(size_t)n * K + k] = f2b(tl[lx][ly + i * 8]);
    }
}

__global__ __launch_bounds__(256) void k0_all(
    const float* __restrict__ W0, const float* __restrict__ Wc1,
    const float* __restrict__ W1, const float* __restrict__ W2,
    const float* __restrict__ wout,
    unsigned short* __restrict__ W0t, unsigned short* __restrict__ W1t,
    unsigned short* __restrict__ W2t, float* __restrict__ Mwt)
{
    int bid = blockIdx.x;
    if (bid < 176) {   // W0 symmetrize -> W0t[h][p]
        int g = bid * 256 + threadIdx.x;
        if (g < 128 * KP_) {
            int h = g / KP_, p = g % KP_;
            float w = 0.f;
            if (p < NP_) {
                int i = 0, base = 0;
                while (base + (F_ - i) <= p) { base += F_ - i; ++i; }
                int j = i + (p - base);
                w = W0[(i * F_ + j) * 128 + h];
                if (i != j) w += W0[(j * F_ + i) * 128 + h];
            }
            W0t[g] = f2b(w);
        }
        return;
    }
    bid -= 176;
    if (bid < 338) { transpose_body(W1, W1t, 832, 400, bid % 13, bid / 13); return; }
    bid -= 338;
    if (bid < 169) { transpose_body(W2, W2t, 400, 400, bid % 13, bid / 13); return; }
    bid -= 169;
    // Mwt[j][i] = sum_h Wc1[(i*128+j)*128 + h] * wout[129+h]; pad i=26..31 with 0
    {
        int g = bid * 256 + threadIdx.x;        // 0..4095
        if (g < 128 * 32) {
            int j = g >> 5, i = g & 31;
            float s = 0.f;
            if (i < F_) {
                const float* row = Wc1 + ((size_t)i * 128 + j) * 128;
                for (int h = 0; h < 128; ++h) s = fmaf(row[h], wout[129 + h], s);
            }
            Mwt[g] = s;
        }
    }
}

// ======== K1: 2 b's/block: gather, lin dot, x1 MFMA, cin1 dot, G MFMA ⊙ Mw dot ========
__global__ __launch_bounds__(256) void k1_embed_cin(
    const int*   __restrict__ sparse,
    const float* __restrict__ E,
    const unsigned short* __restrict__ W0t,
    const float* __restrict__ wlin,
    const float* __restrict__ blin,
    const float* __restrict__ wout,
    const float* __restrict__ Mwt,
    unsigned short* __restrict__ vb,
    float* __restrict__ fdot0)
{
    __shared__ __align__(16) unsigned short embB[64][40];   // rows 0-31: b0 (26..31 zero), 32-63: b1
    __shared__ __align__(16) unsigned short Pbuf[64 * 360]; // P[bb*32+d][p]; later overlaid by x1s[bb][h][40]
    __shared__ float wdot[4];
    __shared__ float linv[52];
    __shared__ int   idxs[52];
    __shared__ unsigned char pI[NP_], pJ[NP_];

    const int b0 = blockIdx.x * 2, t = threadIdx.x;

    if (t < 52) {
        int bb = t >= 26 ? 1 : 0, ff = t - bb * 26;
        int id = sparse[(b0 + bb) * F_ + ff];
        idxs[t] = id;
        linv[t] = (float)id * wlin[ff];
    }
    if (t < F_) {
        int i = t, base = F_ * i - (i * (i - 1)) / 2;
        for (int j = i; j < F_; ++j) { pI[base + j - i] = (unsigned char)i; pJ[base + j - i] = (unsigned char)j; }
    }
    __syncthreads();

    // gather 52 rows x 8 float4
    for (int r = t; r < 416; r += 256) {
        int f = r >> 3, q = r & 7;
        int bb = f >= 26 ? 1 : 0, ff = f - bb * 26;
        float4 v4 = *(const float4*)(E + ((size_t)ff * V_ + idxs[f]) * D_ + q * 4);
        uint2 uu; uu.x = pk2t(v4.x, v4.y); uu.y = pk2t(v4.z, v4.w);
        *(uint2*)&embB[bb * 32 + ff][q * 4] = uu;
        *(uint2*)(vb + (size_t)(b0 + bb) * 832 + ff * 32 + q * 4) = uu;
    }
    if (t < 192) {  // zero rows 26..31 & 58..63
        int row = t >> 4, bb = row >= 6 ? 1 : 0, rr = row - bb * 6;
        *(unsigned int*)&embB[bb * 32 + 26 + rr][(t & 15) * 2] = 0u;
    }
    __syncthreads();

    // P[bb*32+d][p] = emb[i][d]*emb[j][d] bf16-trunc
    {
        const int d = t & 31, sub = t >> 5;
        const int bb = sub & 1, pb = sub >> 1;
        const int e0 = bb * 32;
        const int p0 = pb * 88;
        unsigned short* Prow = &Pbuf[(e0 + d) * 360];
        for (int k = 0; k < 44; ++k) {
            int p = p0 + 2 * k;
            float a = bf2f(embB[e0 + pI[p]][d]) * bf2f(embB[e0 + pJ[p]][d]);
            float c = (p + 1 < NP_) ? bf2f(embB[e0 + pI[p + 1]][d]) * bf2f(embB[e0 + pJ[p + 1]][d]) : 0.f;
            *(unsigned int*)&Prow[p] = pk2t(a, c);
        }
    }
    __syncthreads();

    // x1 MFMA: wave: bb = wave&1 (rows bb*32..+31), h-range (wave>>1)*64..+63
    const int wave = t >> 6, lane = t & 63;
    const int lr = lane & 15, lg = lane >> 4;
    const int bb = wave & 1;
    const int h0 = (wave >> 1) * 64;
    f32x4 acc[2][4] = {};
    {
        const unsigned short* Ab = &Pbuf[(bb * 32 + lr) * 360];
        const unsigned short* Bb = W0t + (size_t)(h0 + lr) * KP_ + lg * 8;
        for (int kt = 0; kt < 11; ++kt) {
            const int ko = kt * 32 + lg * 8;
            bf16x8 a0 = *(const bf16x8*)(Ab + ko);
            bf16x8 a1 = *(const bf16x8*)(Ab + 16 * 360 + ko);
#pragma unroll
            for (int n = 0; n < 4; ++n) {
                bf16x8 bw = *(const bf16x8*)(Bb + (size_t)(n * 16) * KP_ + kt * 32);
                acc[0][n] = __builtin_amdgcn_mfma_f32_16x16x32_bf16(a0, bw, acc[0][n], 0, 0, 0);
                acc[1][n] = __builtin_amdgcn_mfma_f32_16x16x32_bf16(a1, bw, acc[1][n], 0, 0, 0);
            }
        }
    }

    // cin1 per-lane dot: s[h] = sum_d x1[h][d], weighted by wout[1+h] (lives on lg==0 lanes)
    float dotv = 0.f;
#pragma unroll
    for (int n = 0; n < 4; ++n) {
        float s = acc[0][n][0] + acc[0][n][1] + acc[0][n][2] + acc[0][n][3]
                + acc[1][n][0] + acc[1][n][1] + acc[1][n][2] + acc[1][n][3];
        s += __shfl_xor(s, 16, 64);
        s += __shfl_xor(s, 32, 64);
        if (lg == 0) dotv += s * wout[1 + h0 + n * 16 + lr];
    }
    __syncthreads();   // all P reads done -> overlay safe

    // x1 -> LDS overlay (x1s[bb][h][40] over Pbuf)
#pragma unroll
    for (int n = 0; n < 4; ++n) {
        const int base = ((bb << 7) + h0 + n * 16 + lr) * 40;
#pragma unroll
        for (int mi = 0; mi < 2; ++mi) {
            *(unsigned int*)&Pbuf[base + mi * 16 + lg * 4]     = pk2t(acc[mi][n][0], acc[mi][n][1]);
            *(unsigned int*)&Pbuf[base + mi * 16 + lg * 4 + 2] = pk2t(acc[mi][n][2], acc[mi][n][3]);
        }
    }
    __syncthreads();

    // G MFMA (f32 accum, never stored) ⊙ Mwt dot folded into dotv
    {
        bf16x8 ga0 = *(const bf16x8*)&embB[bb * 32 + lr][lg * 8];
        bf16x8 ga1 = *(const bf16x8*)&embB[bb * 32 + 16 + lr][lg * 8];
#pragma unroll
        for (int n = 0; n < 4; ++n) {
            const int j = h0 + n * 16 + lr;
            bf16x8 xb = *(const bf16x8*)&Pbuf[((bb << 7) + j) * 40 + lg * 8];
            f32x4 g0 = {}, g1 = {};
            g0 = __builtin_amdgcn_mfma_f32_16x16x32_bf16(ga0, xb, g0, 0, 0, 0);
            g1 = __builtin_amdgcn_mfma_f32_16x16x32_bf16(ga1, xb, g1, 0, 0, 0);
            const float* mr = Mwt + j * 32;
            float4 m0 = *(const float4*)(mr + lg * 4);        // i = lg*4+r
            float4 m1 = *(const float4*)(mr + 16 + lg * 4);   // i = 16+lg*4+r (rows 26..31 are 0)
            dotv += g0[0] * m0.x + g0[1] * m0.y + g0[2] * m0.z + g0[3] * m0.w
                  + g1[0] * m1.x + g1[1] * m1.y + g1[2] * m1.z + g1[3] * m1.w;
        }
    }
#pragma unroll
    for (int off = 1; off <= 32; off <<= 1) dotv += __shfl_xor(dotv, off, 64);
    if (lane == 0) wdot[wave] = dotv;
    __syncthreads();

    if (t < 2) {
        float s = blin[0];
        for (int f = 0; f < F_; ++f) s += linv[t * 26 + f];
        fdot0[b0 + t] = s * wout[0] + wdot[t] + wdot[t + 2];
    }
}

// ======== GEMM core: 64x128 tile, BK=32, reg prefetch ========
static __device__ __forceinline__ void gemm_core(
    const unsigned short* __restrict__ A, int lda,
    const unsigned short* __restrict__ Bt, int ldb, int N,
    int m0, int n0, int kbase, int kend,
    unsigned short (*As)[40], unsigned short (*Bs)[40],
    f32x4 (*acc)[2])
{
    const int t = threadIdx.x;
    const int wave = t >> 6, lane = t & 63;
    const int lr = lane & 15, lg = lane >> 4;
    const int wn = wave * 32;
    const int ar = t >> 2, kg = (t & 3) * 8;

    const unsigned short* aptr = A  + (size_t)(m0 + ar) * lda + kbase + kg;
    const unsigned short* bp0  = Bt + (size_t)(n0 + ar) * ldb + kbase + kg;
    const unsigned short* bp1  = Bt + (size_t)(n0 + 64 + ar) * ldb + kbase + kg;
    const bool bn0 = (n0 + ar) < N, bn1 = (n0 + 64 + ar) < N;
    const uint4 z4 = make_uint4(0u, 0u, 0u, 0u);
    const int nkt = (kend - kbase + 31) >> 5;
    uint4 av, bv0, bv1;
    {
        int k = kbase + kg;
        av  = (k < kend)        ? *(const uint4*)aptr : z4;
        bv0 = (bn0 && k < kend) ? *(const uint4*)bp0  : z4;
        bv1 = (bn1 && k < kend) ? *(const uint4*)bp1  : z4;
    }
    for (int kt = 0; kt < nkt; ++kt) {
        *(uint4*)&As[ar][kg]      = av;
        *(uint4*)&Bs[ar][kg]      = bv0;
        *(uint4*)&Bs[64 + ar][kg] = bv1;
        __syncthreads();
        if (kt + 1 < nkt) {
            int kn = kbase + (kt + 1) * 32 + kg;
            av  = (kn < kend)        ? *(const uint4*)(aptr + (kt + 1) * 32) : z4;
            bv0 = (bn0 && kn < kend) ? *(const uint4*)(bp0  + (kt + 1) * 32) : z4;
            bv1 = (bn1 && kn < kend) ? *(const uint4*)(bp1  + (kt + 1) * 32) : z4;
        }
        bf16x8 af[4], bfr[2];
#pragma unroll
        for (int i = 0; i < 4; ++i) af[i]  = *(const bf16x8*)&As[i * 16 + lr][lg * 8];
#pragma unroll
        for (int j = 0; j < 2; ++j) bfr[j] = *(const bf16x8*)&Bs[wn + j * 16 + lr][lg * 8];
#pragma unroll
        for (int i = 0; i < 4; ++i)
#pragma unroll
            for (int j = 0; j < 2; ++j)
                acc[i][j] = __builtin_amdgcn_mfma_f32_16x16x32_bf16(af[i], bfr[j], acc[i][j], 0, 0, 0);
        __syncthreads();
    }
}

// K2a: h1 = relu(vb@W1+b1) (bf16 out)
__global__ __launch_bounds__(256) void k2_h1(
    const unsigned short* __restrict__ vb, const unsigned short* __restrict__ W1t,
    const float* __restrict__ b1, unsigned short* __restrict__ h1b)
{
    __shared__ __align__(16) unsigned short As[64][40];
    __shared__ __align__(16) unsigned short Bs[128][40];
    const int t = threadIdx.x;
    const int wave = t >> 6, lane = t & 63;
    const int lr = lane & 15, lg = lane >> 4;
    const int m0 = blockIdx.y * 64, n0 = blockIdx.x * 128;
    f32x4 acc[4][2] = {};
    gemm_core(vb, 832, W1t, 832, 400, m0, n0, 0, 832, As, Bs, acc);
#pragma unroll
    for (int i = 0; i < 4; ++i) {
        int mrow = m0 + i * 16 + lg * 4;
#pragma unroll
        for (int j = 0; j < 2; ++j) {
            int col = n0 + wave * 32 + j * 16 + lr;
            if (col >= 400) continue;
            float bb = b1[col];
#pragma unroll
            for (int r = 0; r < 4; ++r)
                h1b[(size_t)(mrow + r) * 400 + col] = f2bt(fmaxf(acc[i][j][r] + bb, 0.f));
        }
    }
}

// K2b: h2 never materialized — bias+relu+dot(wout) -> pdh2[nb][b]
__global__ __launch_bounds__(256) void k2_h2(
    const unsigned short* __restrict__ h1b, const unsigned short* __restrict__ W2t,
    const float* __restrict__ b2, const float* __restrict__ wout,
    float* __restrict__ pdh2)
{
    __shared__ __align__(16) unsigned short As[64][40];
    __shared__ __align__(16) unsigned short Bs[128][40];
    __shared__ float red[4][64];
    const int t = threadIdx.x;
    const int wave = t >> 6, lane = t & 63;
    const int lr = lane & 15, lg = lane >> 4;
    const int m0 = blockIdx.y * 64, n0 = blockIdx.x * 128;
    f32x4 acc[4][2] = {};
    gemm_core(h1b, 400, W2t, 400, 400, m0, n0, 0, 400, As, Bs, acc);
    float v[4][4];
#pragma unroll
    for (int i = 0; i < 4; ++i)
#pragma unroll
        for (int r = 0; r < 4; ++r) {
            float s = 0.f;
#pragma unroll
            for (int j = 0; j < 2; ++j) {
                int col = n0 + wave * 32 + j * 16 + lr;
                if (col < 400)
                    s = fmaf(fmaxf(acc[i][j][r] + b2[col], 0.f), wout[257 + col], s);
            }
#pragma unroll
            for (int off = 1; off <= 8; off <<= 1) s += __shfl_xor(s, off, 64);
            v[i][r] = s;
        }
    if (lr == 0) {
#pragma unroll
        for (int i = 0; i < 4; ++i)
#pragma unroll
            for (int r = 0; r < 4; ++r) red[wave][i * 16 + lg * 4 + r] = v[i][r];
    }
    __syncthreads();
    if (t < 64) pdh2[(size_t)blockIdx.x * B_ + m0 + t] = red[0][t] + red[1][t] + red[2][t] + red[3][t];
}

// ======== K3: sum partials + dense dot + sigmoid ========
__global__ __launch_bounds__(256) void k3_final(
    const float* __restrict__ fdot0,
    const float* __restrict__ pdh2,
    const float* __restrict__ dense,
    const float* __restrict__ wout,
    const float* __restrict__ bout,
    float* __restrict__ out)
{
    const int b = blockIdx.x * 256 + threadIdx.x;
    float s = fdot0[b];
#pragma unroll
    for (int z = 0; z < 4; ++z) s += pdh2[(size_t)z * B_ + b];
#pragma unroll
    for (int q = 0; q < 13; ++q) s = fmaf(dense[(size_t)b * 13 + q], wout[657 + q], s);
    out[b] = 1.f / (1.f + expf(-(s + bout[0])));
}

extern "C" void kernel_launch(void* const* d_in, const int* in_sizes, int n_in,
                              void* d_out, int out_size, void* d_ws, size_t ws_size,
                              hipStream_t stream) {
    const float* dense  = (const float*)d_in[0];
    const int*   sparse = (const int*)  d_in[1];
    const float* E      = (const float*)d_in[2];
    const float* W0     = (const float*)d_in[3];
    const float* Wc1    = (const float*)d_in[4];
    const float* W1     = (const float*)d_in[5];
    const float* b1     = (const float*)d_in[6];
    const float* W2     = (const float*)d_in[7];
    const float* b2     = (const float*)d_in[8];
    const float* wlin   = (const float*)d_in[9];
    const float* blin   = (const float*)d_in[10];
    const float* wout   = (const float*)d_in[11];
    const float* bout   = (const float*)d_in[12];
    float* out = (float*)d_out;

    char* ws = (char*)d_ws;
    unsigned short* vb    = (unsigned short*)(ws + OFF_VB);
    float*          fdot0 = (float*)(ws + OFF_FD0);
    float*          pdh2  = (float*)(ws + OFF_PDH2);
    unsigned short* h1b   = (unsigned short*)(ws + OFF_H1B);
    unsigned short* W0t   = (unsigned short*)(ws + OFF_W0T);
    unsigned short* W1t   = (unsigned short*)(ws + OFF_W1T);
    unsigned short* W2t   = (unsigned short*)(ws + OFF_W2T);
    float*          Mwt   = (float*)(ws + OFF_MWT);

    k0_all<<<176 + 338 + 169 + 16, 256, 0, stream>>>(W0, Wc1, W1, W2, wout, W0t, W1t, W2t, Mwt);
    k1_embed_cin<<<B_ / 2, 256, 0, stream>>>(sparse, E, W0t, wlin, blin, wout, Mwt, vb, fdot0);
    k2_h1<<<dim3(4, 128), 256, 0, stream>>>(vb, W1t, b1, h1b);
    k2_h2<<<dim3(4, 128), 256, 0, stream>>>(h1b, W2t, b2, wout, pdh2);
    k3_final<<<B_ / 256, 256, 0, stream>>>(fdot0, pdh2, dense, wout, bout, out);
}